// Round 2
// baseline (18813.033 us; speedup 1.0000x reference)
//
#include <hip/hip_runtime.h>
#include <math.h>

// Sizes fixed by setup_inputs(): H=2048, IN=128, OUT=128, T=512, STEPS=64
#define H    2048
#define IN_  128
#define OUT_ 128
#define T_   512
#define STEPS 64

// ---------------------------------------------------------------------------
// Generic tiled GEMM: C[M,N] = A[M,K] @ B[N,K]^T + bias[N]   (all row-major)
// ---------------------------------------------------------------------------
#define BM 64
#define BN 64
#define BK 16
__global__ __launch_bounds__(256) void gemm_abt(
    const float* __restrict__ A, const float* __restrict__ B,
    const float* __restrict__ bias, float* __restrict__ C,
    int M, int N, int K)
{
    __shared__ float As[BM][BK + 1];
    __shared__ float Bs[BN][BK + 1];
    int tid = threadIdx.x;
    int m0 = blockIdx.y * BM, n0 = blockIdx.x * BN;
    int ty = tid / 16, tx = tid % 16;
    float acc[4][4] = {};
    int r = tid >> 2, q = tid & 3;
    for (int k0 = 0; k0 < K; k0 += BK) {
        float4 a4 = *(const float4*)(A + (size_t)(m0 + r) * K + k0 + q * 4);
        As[r][q * 4 + 0] = a4.x; As[r][q * 4 + 1] = a4.y;
        As[r][q * 4 + 2] = a4.z; As[r][q * 4 + 3] = a4.w;
        float4 b4 = *(const float4*)(B + (size_t)(n0 + r) * K + k0 + q * 4);
        Bs[r][q * 4 + 0] = b4.x; Bs[r][q * 4 + 1] = b4.y;
        Bs[r][q * 4 + 2] = b4.z; Bs[r][q * 4 + 3] = b4.w;
        __syncthreads();
#pragma unroll
        for (int kk = 0; kk < BK; kk++) {
            float a[4], b[4];
#pragma unroll
            for (int i = 0; i < 4; i++) a[i] = As[ty * 4 + i][kk];
#pragma unroll
            for (int j = 0; j < 4; j++) b[j] = Bs[tx * 4 + j][kk];
#pragma unroll
            for (int i = 0; i < 4; i++)
#pragma unroll
                for (int j = 0; j < 4; j++) acc[i][j] += a[i] * b[j];
        }
        __syncthreads();
    }
#pragma unroll
    for (int i = 0; i < 4; i++)
#pragma unroll
        for (int j = 0; j < 4; j++)
            C[(size_t)(m0 + ty * 4 + i) * N + n0 + tx * 4 + j] =
                acc[i][j] + bias[n0 + tx * 4 + j];
}

// ---------------------------------------------------------------------------
// Persistent encoder: 256 blocks x 512 threads, 1 block/CU.
// Block b owns hidden units j0=8b..j0+7 (24 rows of Whh, register-resident:
// 96 float4/lane). Per step: h -> LDS, register dots, grid barrier.
// enc_out[-H .. -1] must be a zero row (h_0 = 0).
// ctrl[0]=arrival counter, ctrl[1]=release flag (both zeroed per call).
// ---------------------------------------------------------------------------
__global__ __launch_bounds__(512, 2) void enc_persistent(
    const float* __restrict__ Whh, const float* __restrict__ bhh,
    const float* __restrict__ gi_all, float* __restrict__ enc_out,
    unsigned* __restrict__ ctrl)
{
    __shared__ float h_s[H];
    __shared__ float red_s[24];
    const int tid = threadIdx.x;
    const int wv = tid >> 6, ln = tid & 63;
    const int j0 = blockIdx.x * 8;
    const unsigned nblk = gridDim.x;

    // ---- one-time: weights -> registers (coalesced float4 loads) ----
    float4 wreg[3][8];
    float bias[3];
    int sidx[3];
#pragma unroll
    for (int i = 0; i < 3; i++) {
        int ridx = wv * 3 + i;            // 0..23
        int u = ridx & 7, g = ridx >> 3;  // gate 0=r,1=z,2=n
        int row = g * H + j0 + u;
        const float4* wr = (const float4*)(Whh + (size_t)row * H);
#pragma unroll
        for (int m = 0; m < 8; m++) wreg[i][m] = wr[ln + (m << 6)];
        bias[i] = bhh[row];
        sidx[i] = g * 8 + u;
    }

    for (int t = 0; t < T_; t++) {
        // h_{t-1} -> LDS (t=0 reads the zero row)
        const float4* hprev = (const float4*)(enc_out + (size_t)(t - 1) * H);
        ((float4*)h_s)[tid] = hprev[tid];
        float ir = 0.f, iz = 0.f, inn = 0.f;
        if (tid < 8) {  // prefetch gi for this block's units
            const float* gi = gi_all + (size_t)t * 3 * H;
            ir  = gi[j0 + tid];
            iz  = gi[H + j0 + tid];
            inn = gi[2 * H + j0 + tid];
        }
        __syncthreads();

        float s0 = 0.f, s1 = 0.f, s2 = 0.f;
#pragma unroll
        for (int m = 0; m < 8; m++) {
            float4 h4 = ((const float4*)h_s)[ln + (m << 6)];
            s0 += wreg[0][m].x * h4.x + wreg[0][m].y * h4.y +
                  wreg[0][m].z * h4.z + wreg[0][m].w * h4.w;
            s1 += wreg[1][m].x * h4.x + wreg[1][m].y * h4.y +
                  wreg[1][m].z * h4.z + wreg[1][m].w * h4.w;
            s2 += wreg[2][m].x * h4.x + wreg[2][m].y * h4.y +
                  wreg[2][m].z * h4.z + wreg[2][m].w * h4.w;
        }
#pragma unroll
        for (int off = 32; off; off >>= 1) {
            s0 += __shfl_xor(s0, off, 64);
            s1 += __shfl_xor(s1, off, 64);
            s2 += __shfl_xor(s2, off, 64);
        }
        if (ln == 0) {
            red_s[sidx[0]] = s0 + bias[0];
            red_s[sidx[1]] = s1 + bias[1];
            red_s[sidx[2]] = s2 + bias[2];
        }
        __syncthreads();

        if (tid < 8) {
            float hr = red_s[tid], hz = red_s[8 + tid], hn = red_s[16 + tid];
            float rg = 1.f / (1.f + expf(-(ir + hr)));
            float zg = 1.f / (1.f + expf(-(iz + hz)));
            float ng = tanhf(inn + rg * hn);
            enc_out[(size_t)t * H + j0 + tid] =
                (1.f - zg) * ng + zg * h_s[j0 + tid];
        }

        // ---- grid barrier (monotonic counter + release flag) ----
        __syncthreads();
        if (tid == 0) {
            __threadfence();
            unsigned arrived = __hip_atomic_fetch_add(
                &ctrl[0], 1u, __ATOMIC_ACQ_REL, __HIP_MEMORY_SCOPE_AGENT);
            unsigned want = nblk * (unsigned)(t + 1);
            if (arrived == want - 1u) {
                __hip_atomic_store(&ctrl[1], (unsigned)(t + 1),
                                   __ATOMIC_RELEASE, __HIP_MEMORY_SCOPE_AGENT);
            } else {
                while (__hip_atomic_load(&ctrl[1], __ATOMIC_ACQUIRE,
                                         __HIP_MEMORY_SCOPE_AGENT) <
                       (unsigned)(t + 1))
                    __builtin_amdgcn_s_sleep(1);
            }
        }
        __syncthreads();
    }
}

// ---------------------------------------------------------------------------
// Decoder GRU step (unchanged from round 1).
// ---------------------------------------------------------------------------
__global__ __launch_bounds__(512) void dec_gru_kernel(
    const float* __restrict__ Wih, const float* __restrict__ Whh,
    const float* __restrict__ bih, const float* __restrict__ bhh,
    const float* __restrict__ din, const float* __restrict__ h_prev,
    float* __restrict__ h_out)
{
    __shared__ float d_s[2 * H];
    __shared__ float h_s[H];
    __shared__ float red_s[48];
    int tid = threadIdx.x;
    ((float4*)d_s)[tid]       = ((const float4*)din)[tid];
    ((float4*)d_s)[tid + 512] = ((const float4*)din)[tid + 512];
    ((float4*)h_s)[tid]       = ((const float4*)h_prev)[tid];
    __syncthreads();
    int wave = tid >> 6, lane = tid & 63;
    int j0 = blockIdx.x * 8;
#pragma unroll
    for (int i = 0; i < 6; i++) {
        int ridx = i * 8 + wave;
        int big = (ridx < 24);
        int rr = big ? ridx : ridx - 24;
        int u = rr & 7, g = rr >> 3;
        int row = g * H + j0 + u;
        float sum = 0.f, bs;
        if (big) {
            const float4* wr = (const float4*)(Wih + (size_t)row * (2 * H));
            const float4* dv = (const float4*)d_s;
#pragma unroll
            for (int k = 0; k < 16; k++) {
                float4 w4 = wr[lane + 64 * k];
                float4 v4 = dv[lane + 64 * k];
                sum += w4.x * v4.x + w4.y * v4.y + w4.z * v4.z + w4.w * v4.w;
            }
            bs = bih[row];
        } else {
            const float4* wr = (const float4*)(Whh + (size_t)row * H);
            const float4* hv = (const float4*)h_s;
#pragma unroll
            for (int k = 0; k < 8; k++) {
                float4 w4 = wr[lane + 64 * k];
                float4 h4 = hv[lane + 64 * k];
                sum += w4.x * h4.x + w4.y * h4.y + w4.z * h4.z + w4.w * h4.w;
            }
            bs = bhh[row];
        }
#pragma unroll
        for (int off = 32; off; off >>= 1) sum += __shfl_xor(sum, off, 64);
        if (lane == 0) red_s[ridx] = sum + bs;
    }
    __syncthreads();
    if (tid < 8) {
        int j = j0 + tid;
        float ir = red_s[tid], iz = red_s[8 + tid], inn = red_s[16 + tid];
        float hr = red_s[24 + tid], hz = red_s[32 + tid], hn = red_s[40 + tid];
        float rg = 1.f / (1.f + expf(-(ir + hr)));
        float zg = 1.f / (1.f + expf(-(iz + hz)));
        float ng = tanhf(inn + rg * hn);
        h_out[j] = (1.f - zg) * ng + zg * h_s[j];
    }
}

__global__ __launch_bounds__(512) void matvec_kernel(
    const float* __restrict__ W, const float* __restrict__ v,
    const float* __restrict__ bias, float* __restrict__ out,
    int nrows, int K)
{
    __shared__ float v_s[4096];
    int tid = threadIdx.x;
    for (int i = tid; i < (K >> 2); i += blockDim.x)
        ((float4*)v_s)[i] = ((const float4*)v)[i];
    __syncthreads();
    int lane = tid & 63;
    int gw = (blockIdx.x * blockDim.x + tid) >> 6;
    int nw = (gridDim.x * blockDim.x) >> 6;
    int kq = K >> 2;
    for (int row = gw; row < nrows; row += nw) {
        const float4* wr = (const float4*)(W + (size_t)row * K);
        const float4* vv = (const float4*)v_s;
        float sum = 0.f;
        for (int k = lane; k < kq; k += 64) {
            float4 w4 = wr[k]; float4 h4 = vv[k];
            sum += w4.x * h4.x + w4.y * h4.y + w4.z * h4.z + w4.w * h4.w;
        }
#pragma unroll
        for (int off = 32; off; off >>= 1) sum += __shfl_xor(sum, off, 64);
        if (lane == 0) out[row] = sum + bias[row];
    }
}

__global__ __launch_bounds__(256) void scores_kernel(
    const float* __restrict__ U, const float* __restrict__ Wd,
    const float* __restrict__ attn_W, const float* __restrict__ attn_b,
    float* __restrict__ scores)
{
    int t = blockIdx.x, tid = threadIdx.x;
    int wave = tid >> 6, lane = tid & 63;
    const float* Ut = U + (size_t)t * H;
    float p = 0.f;
    for (int j = tid; j < H; j += 256)
        p += tanhf(Ut[j] + Wd[j]) * attn_W[j];
#pragma unroll
    for (int off = 32; off; off >>= 1) p += __shfl_xor(p, off, 64);
    __shared__ float ws_[4];
    if (lane == 0) ws_[wave] = p;
    __syncthreads();
    if (tid == 0) scores[t] = ws_[0] + ws_[1] + ws_[2] + ws_[3] + attn_b[0];
}

__global__ __launch_bounds__(512) void softmax_kernel(
    const float* __restrict__ scores, float* __restrict__ aw,
    float* __restrict__ attn_out, float* __restrict__ din_ctx)
{
    __shared__ float red[8];
    __shared__ float m_sh, s_sh;
    int tid = threadIdx.x, wave = tid >> 6, lane = tid & 63;
    float s = scores[tid];
    float m = s;
#pragma unroll
    for (int off = 32; off; off >>= 1) m = fmaxf(m, __shfl_xor(m, off, 64));
    if (lane == 0) red[wave] = m;
    __syncthreads();
    if (tid == 0) {
        float mm = red[0];
        for (int i = 1; i < 8; i++) mm = fmaxf(mm, red[i]);
        m_sh = mm;
    }
    __syncthreads();
    float e = expf(s - m_sh);
    float p = e;
#pragma unroll
    for (int off = 32; off; off >>= 1) p += __shfl_xor(p, off, 64);
    if (lane == 0) red[wave] = p;
    __syncthreads();
    if (tid == 0) {
        float ss = 0.f;
        for (int i = 0; i < 8; i++) ss += red[i];
        s_sh = ss;
    }
    __syncthreads();
    float a = e / s_sh;
    aw[tid] = a;
    attn_out[tid] = a;
    din_ctx[tid] = 0.f; din_ctx[tid + 512] = 0.f;
    din_ctx[tid + 1024] = 0.f; din_ctx[tid + 1536] = 0.f;
}

__global__ __launch_bounds__(256) void ctx_kernel(
    const float* __restrict__ aw, const float* __restrict__ enc_out,
    float* __restrict__ din_ctx)
{
    int j = blockIdx.x * 256 + threadIdx.x;
    int t0 = blockIdx.y * 128;
    __shared__ float aw_s[128];
    if (threadIdx.x < 128) aw_s[threadIdx.x] = aw[t0 + threadIdx.x];
    __syncthreads();
    float acc = 0.f;
#pragma unroll 8
    for (int t = 0; t < 128; t++)
        acc += aw_s[t] * enc_out[(size_t)(t0 + t) * H + j];
    atomicAdd(&din_ctx[j], acc);
}

__global__ __launch_bounds__(256) void logits_kernel(
    const float* __restrict__ h2o_W, const float* __restrict__ h2o_b,
    const float* __restrict__ h2,
    const float* __restrict__ o2h_W, const float* __restrict__ o2h_b,
    float* __restrict__ out_row, float* __restrict__ din_emb)
{
    __shared__ float h_s[H];
    __shared__ float lg[OUT_];
    __shared__ float m_s, ls_s;
    __shared__ int am_s;
    int tid = threadIdx.x;
    ((float4*)h_s)[tid]       = ((const float4*)h2)[tid];
    ((float4*)h_s)[tid + 256] = ((const float4*)h2)[tid + 256];
    __syncthreads();
    int wave = tid >> 6, lane = tid & 63;
#pragma unroll
    for (int i = 0; i < 32; i++) {
        int row = i * 4 + wave;
        const float4* wr = (const float4*)(h2o_W + (size_t)row * H);
        const float4* hv = (const float4*)h_s;
        float sum = 0.f;
#pragma unroll
        for (int k = 0; k < 8; k++) {
            float4 w4 = wr[lane + 64 * k];
            float4 h4 = hv[lane + 64 * k];
            sum += w4.x * h4.x + w4.y * h4.y + w4.z * h4.z + w4.w * h4.w;
        }
#pragma unroll
        for (int off = 32; off; off >>= 1) sum += __shfl_xor(sum, off, 64);
        if (lane == 0) lg[row] = sum + h2o_b[row];
    }
    __syncthreads();
    if (tid == 0) {
        float m = lg[0]; int am = 0;
        for (int i = 1; i < OUT_; i++)
            if (lg[i] > m) { m = lg[i]; am = i; }
        float ss = 0.f;
        for (int i = 0; i < OUT_; i++) ss += expf(lg[i] - m);
        m_s = m; ls_s = logf(ss); am_s = am;
    }
    __syncthreads();
    if (tid < OUT_) out_row[tid] = (lg[tid] - m_s) - ls_s;
    int am = am_s;
    for (int j = tid; j < H; j += 256)
        din_emb[j] = o2h_W[(size_t)j * OUT_ + am] + o2h_b[j];
}

__global__ void copy_kernel(float* dst, const float* src, int n) {
    int i = blockIdx.x * blockDim.x + threadIdx.x;
    if (i < n) dst[i] = src[i];
}

extern "C" void kernel_launch(void* const* d_in, const int* in_sizes, int n_in,
                              void* d_out, int out_size, void* d_ws, size_t ws_size,
                              hipStream_t stream)
{
    const float* x     = (const float*)d_in[0];
    const float* eWih  = (const float*)d_in[1];
    const float* eWhh  = (const float*)d_in[2];
    const float* ebih  = (const float*)d_in[3];
    const float* ebhh  = (const float*)d_in[4];
    const float* dWih  = (const float*)d_in[5];
    const float* dWhh  = (const float*)d_in[6];
    const float* dbih  = (const float*)d_in[7];
    const float* dbhh  = (const float*)d_in[8];
    const float* h2oW  = (const float*)d_in[9];
    const float* h2ob  = (const float*)d_in[10];
    const float* UW    = (const float*)d_in[11];
    const float* Ub    = (const float*)d_in[12];
    const float* WW    = (const float*)d_in[13];
    const float* Wb    = (const float*)d_in[14];
    const float* attnW = (const float*)d_in[15];
    const float* attnb = (const float*)d_in[16];
    const float* o2hW  = (const float*)d_in[17];
    const float* o2hb  = (const float*)d_in[18];

    float* ws      = (float*)d_ws;
    unsigned* ctrl = (unsigned*)ws;                    // [0]=cnt [1]=flag (16 floats reserved)
    float* zrow    = ws + 16;                          // 2048 zeros (h_0)
    float* enc_out = zrow + H;                         // 512*2048; enc_out[-H]=zrow
    float* gi_all  = enc_out + (size_t)T_ * H;         // 512*6144
    float* U       = gi_all + (size_t)T_ * 3 * H;      // 512*2048
    float* Wd      = U + (size_t)T_ * H;               // 2048
    float* scores  = Wd + H;                           // 512
    float* aw      = scores + T_;                      // 512
    float* din     = aw + T_;                          // 4096
    float* hd      = din + 2 * H;                      // 2*2048

    float* outs  = (float*)d_out;                      // 64*128
    float* attns = outs + STEPS * OUT_;                // 64*512

    // zero barrier ctrl + h0 row (d_ws is poisoned 0xAA before every call)
    hipMemsetAsync(d_ws, 0, (16 + H) * sizeof(float), stream);

    // ---- encoder ----
    // gi_all = x @ eWih^T + ebih   (M=512, N=6144, K=128)
    gemm_abt<<<dim3(3 * H / BN, T_ / BM), 256, 0, stream>>>(
        x, eWih, ebih, gi_all, T_, 3 * H, IN_);
    enc_persistent<<<256, 512, 0, stream>>>(eWhh, ebhh, gi_all, enc_out, ctrl);

    // U = enc_out @ UW^T + Ub   (M=512, N=2048, K=2048)
    gemm_abt<<<dim3(H / BN, T_ / BM), 256, 0, stream>>>(
        enc_out, UW, Ub, U, T_, H, H);

    // ---- decoder ----
    copy_kernel<<<8, 256, 0, stream>>>(din, o2hb, H);  // emb for step 0 (inp=0)
    const float* h = enc_out + (size_t)(T_ - 1) * H;
    for (int s = 0; s < STEPS; s++) {
        matvec_kernel<<<64, 512, 0, stream>>>(WW, h, Wb, Wd, H, H);
        scores_kernel<<<T_, 256, 0, stream>>>(U, Wd, attnW, attnb, scores);
        softmax_kernel<<<1, 512, 0, stream>>>(scores, aw, attns + (size_t)s * T_,
                                              din + H);
        ctx_kernel<<<dim3(8, 4), 256, 0, stream>>>(aw, enc_out, din + H);
        float* hn = hd + (s & 1) * H;
        dec_gru_kernel<<<256, 512, 0, stream>>>(dWih, dWhh, dbih, dbhh, din, h, hn);
        logits_kernel<<<1, 256, 0, stream>>>(h2oW, h2ob, hn, o2hW, o2hb,
                                             outs + (size_t)s * OUT_, din);
        h = hn;
    }
}

// Round 3
// 16559.071 us; speedup vs baseline: 1.1361x; 1.1361x over previous
//
#include <hip/hip_runtime.h>
#include <math.h>

// Sizes fixed by setup_inputs(): H=2048, IN=128, OUT=128, T=512, STEPS=64
#define H    2048
#define IN_  128
#define OUT_ 128
#define T_   512
#define STEPS 64

// ---------------------------------------------------------------------------
// Generic tiled GEMM: C[M,N] = A[M,K] @ B[N,K]^T + bias[N]   (all row-major)
// ---------------------------------------------------------------------------
#define BM 64
#define BN 64
#define BK 16
__global__ __launch_bounds__(256) void gemm_abt(
    const float* __restrict__ A, const float* __restrict__ B,
    const float* __restrict__ bias, float* __restrict__ C,
    int M, int N, int K)
{
    __shared__ float As[BM][BK + 1];
    __shared__ float Bs[BN][BK + 1];
    int tid = threadIdx.x;
    int m0 = blockIdx.y * BM, n0 = blockIdx.x * BN;
    int ty = tid / 16, tx = tid % 16;
    float acc[4][4] = {};
    int r = tid >> 2, q = tid & 3;
    for (int k0 = 0; k0 < K; k0 += BK) {
        float4 a4 = *(const float4*)(A + (size_t)(m0 + r) * K + k0 + q * 4);
        As[r][q * 4 + 0] = a4.x; As[r][q * 4 + 1] = a4.y;
        As[r][q * 4 + 2] = a4.z; As[r][q * 4 + 3] = a4.w;
        float4 b4 = *(const float4*)(B + (size_t)(n0 + r) * K + k0 + q * 4);
        Bs[r][q * 4 + 0] = b4.x; Bs[r][q * 4 + 1] = b4.y;
        Bs[r][q * 4 + 2] = b4.z; Bs[r][q * 4 + 3] = b4.w;
        __syncthreads();
#pragma unroll
        for (int kk = 0; kk < BK; kk++) {
            float a[4], b[4];
#pragma unroll
            for (int i = 0; i < 4; i++) a[i] = As[ty * 4 + i][kk];
#pragma unroll
            for (int j = 0; j < 4; j++) b[j] = Bs[tx * 4 + j][kk];
#pragma unroll
            for (int i = 0; i < 4; i++)
#pragma unroll
                for (int j = 0; j < 4; j++) acc[i][j] += a[i] * b[j];
        }
        __syncthreads();
    }
#pragma unroll
    for (int i = 0; i < 4; i++)
#pragma unroll
        for (int j = 0; j < 4; j++)
            C[(size_t)(m0 + ty * 4 + i) * N + n0 + tx * 4 + j] =
                acc[i][j] + bias[n0 + tx * 4 + j];
}

// ---------------------------------------------------------------------------
// Persistent encoder: 256 blocks x 512 threads, 1 block/CU.
// Block b owns hidden units j0=8b..j0+7 (24 rows of Whh, register-resident:
// 24 float4/lane = 96 VGPRs). Per step: h -> LDS, register dots, barrier.
//
// Barrier: arrival-slot broadcast, NO RMW. Block b's tid0: release fence +
// relaxed store ctrl[b]=t+1 (monotonic -> no reset race). Threads tid<256 of
// every block poll all 256 slots with RELAXED agent loads (agent scope sets
// the coherent-read flags; relaxed avoids a cache-inv per poll iteration),
// then one acquire fence. Round-2 lesson: 256-deep fetch_add chain + acquire
// per spin iteration cost ~30us/step.
// ---------------------------------------------------------------------------
__global__ __launch_bounds__(512, 2) void enc_persistent(
    const float* __restrict__ Whh, const float* __restrict__ bhh,
    const float* __restrict__ gi_all, float* __restrict__ enc_out,
    unsigned* __restrict__ ctrl)
{
    __shared__ float h_s[H];
    __shared__ float red_s[24];
    const int tid = threadIdx.x;
    const int wv = tid >> 6, ln = tid & 63;
    const int j0 = blockIdx.x * 8;

    // ---- one-time: weights -> registers (coalesced float4 loads) ----
    float4 wreg[3][8];
    float bias[3];
    int sidx[3];
#pragma unroll
    for (int i = 0; i < 3; i++) {
        int ridx = wv * 3 + i;            // 0..23
        int u = ridx & 7, g = ridx >> 3;  // gate 0=r,1=z,2=n
        int row = g * H + j0 + u;
        const float4* wr = (const float4*)(Whh + (size_t)row * H);
#pragma unroll
        for (int m = 0; m < 8; m++) wreg[i][m] = wr[ln + (m << 6)];
        bias[i] = bhh[row];
        sidx[i] = g * 8 + u;
    }

    for (int t = 0; t < T_; t++) {
        // h_{t-1} -> LDS (t=0 reads the zero row at enc_out[-H])
        const float4* hprev = (const float4*)(enc_out + (size_t)(t - 1) * H);
        ((float4*)h_s)[tid] = hprev[tid];
        float ir = 0.f, iz = 0.f, inn = 0.f;
        if (tid < 8) {
            const float* gi = gi_all + (size_t)t * 3 * H;
            ir  = gi[j0 + tid];
            iz  = gi[H + j0 + tid];
            inn = gi[2 * H + j0 + tid];
        }
        __syncthreads();

        float s0 = 0.f, s1 = 0.f, s2 = 0.f;
#pragma unroll
        for (int m = 0; m < 8; m++) {
            float4 h4 = ((const float4*)h_s)[ln + (m << 6)];
            s0 += wreg[0][m].x * h4.x + wreg[0][m].y * h4.y +
                  wreg[0][m].z * h4.z + wreg[0][m].w * h4.w;
            s1 += wreg[1][m].x * h4.x + wreg[1][m].y * h4.y +
                  wreg[1][m].z * h4.z + wreg[1][m].w * h4.w;
            s2 += wreg[2][m].x * h4.x + wreg[2][m].y * h4.y +
                  wreg[2][m].z * h4.z + wreg[2][m].w * h4.w;
        }
#pragma unroll
        for (int off = 32; off; off >>= 1) {
            s0 += __shfl_xor(s0, off, 64);
            s1 += __shfl_xor(s1, off, 64);
            s2 += __shfl_xor(s2, off, 64);
        }
        if (ln == 0) {
            red_s[sidx[0]] = s0 + bias[0];
            red_s[sidx[1]] = s1 + bias[1];
            red_s[sidx[2]] = s2 + bias[2];
        }
        __syncthreads();

        if (tid < 8) {
            float hr = red_s[tid], hz = red_s[8 + tid], hn = red_s[16 + tid];
            float rg = 1.f / (1.f + expf(-(ir + hr)));
            float zg = 1.f / (1.f + expf(-(iz + hz)));
            float ng = tanhf(inn + rg * hn);
            enc_out[(size_t)t * H + j0 + tid] =
                (1.f - zg) * ng + zg * h_s[j0 + tid];
        }

        // ---- slot-broadcast grid barrier ----
        __syncthreads();
        if (tid == 0) {
            __builtin_amdgcn_fence(__ATOMIC_RELEASE, "agent");
            __hip_atomic_store(&ctrl[blockIdx.x], (unsigned)(t + 1),
                               __ATOMIC_RELAXED, __HIP_MEMORY_SCOPE_AGENT);
        }
        if (tid < 256) {
            while (__hip_atomic_load(&ctrl[tid], __ATOMIC_RELAXED,
                                     __HIP_MEMORY_SCOPE_AGENT) <
                   (unsigned)(t + 1))
                __builtin_amdgcn_s_sleep(2);
        }
        __builtin_amdgcn_fence(__ATOMIC_ACQUIRE, "agent");
        __syncthreads();
    }
}

// ---------------------------------------------------------------------------
// Decoder GRU step (unchanged).
// ---------------------------------------------------------------------------
__global__ __launch_bounds__(512) void dec_gru_kernel(
    const float* __restrict__ Wih, const float* __restrict__ Whh,
    const float* __restrict__ bih, const float* __restrict__ bhh,
    const float* __restrict__ din, const float* __restrict__ h_prev,
    float* __restrict__ h_out)
{
    __shared__ float d_s[2 * H];
    __shared__ float h_s[H];
    __shared__ float red_s[48];
    int tid = threadIdx.x;
    ((float4*)d_s)[tid]       = ((const float4*)din)[tid];
    ((float4*)d_s)[tid + 512] = ((const float4*)din)[tid + 512];
    ((float4*)h_s)[tid]       = ((const float4*)h_prev)[tid];
    __syncthreads();
    int wave = tid >> 6, lane = tid & 63;
    int j0 = blockIdx.x * 8;
#pragma unroll
    for (int i = 0; i < 6; i++) {
        int ridx = i * 8 + wave;
        int big = (ridx < 24);
        int rr = big ? ridx : ridx - 24;
        int u = rr & 7, g = rr >> 3;
        int row = g * H + j0 + u;
        float sum = 0.f, bs;
        if (big) {
            const float4* wr = (const float4*)(Wih + (size_t)row * (2 * H));
            const float4* dv = (const float4*)d_s;
#pragma unroll
            for (int k = 0; k < 16; k++) {
                float4 w4 = wr[lane + 64 * k];
                float4 v4 = dv[lane + 64 * k];
                sum += w4.x * v4.x + w4.y * v4.y + w4.z * v4.z + w4.w * v4.w;
            }
            bs = bih[row];
        } else {
            const float4* wr = (const float4*)(Whh + (size_t)row * H);
            const float4* hv = (const float4*)h_s;
#pragma unroll
            for (int k = 0; k < 8; k++) {
                float4 w4 = wr[lane + 64 * k];
                float4 h4 = hv[lane + 64 * k];
                sum += w4.x * h4.x + w4.y * h4.y + w4.z * h4.z + w4.w * h4.w;
            }
            bs = bhh[row];
        }
#pragma unroll
        for (int off = 32; off; off >>= 1) sum += __shfl_xor(sum, off, 64);
        if (lane == 0) red_s[ridx] = sum + bs;
    }
    __syncthreads();
    if (tid < 8) {
        int j = j0 + tid;
        float ir = red_s[tid], iz = red_s[8 + tid], inn = red_s[16 + tid];
        float hr = red_s[24 + tid], hz = red_s[32 + tid], hn = red_s[40 + tid];
        float rg = 1.f / (1.f + expf(-(ir + hr)));
        float zg = 1.f / (1.f + expf(-(iz + hz)));
        float ng = tanhf(inn + rg * hn);
        h_out[j] = (1.f - zg) * ng + zg * h_s[j];
    }
}

__global__ __launch_bounds__(512) void matvec_kernel(
    const float* __restrict__ W, const float* __restrict__ v,
    const float* __restrict__ bias, float* __restrict__ out,
    int nrows, int K)
{
    __shared__ float v_s[4096];
    int tid = threadIdx.x;
    for (int i = tid; i < (K >> 2); i += blockDim.x)
        ((float4*)v_s)[i] = ((const float4*)v)[i];
    __syncthreads();
    int lane = tid & 63;
    int gw = (blockIdx.x * blockDim.x + tid) >> 6;
    int nw = (gridDim.x * blockDim.x) >> 6;
    int kq = K >> 2;
    for (int row = gw; row < nrows; row += nw) {
        const float4* wr = (const float4*)(W + (size_t)row * K);
        const float4* vv = (const float4*)v_s;
        float sum = 0.f;
        for (int k = lane; k < kq; k += 64) {
            float4 w4 = wr[k]; float4 h4 = vv[k];
            sum += w4.x * h4.x + w4.y * h4.y + w4.z * h4.z + w4.w * h4.w;
        }
#pragma unroll
        for (int off = 32; off; off >>= 1) sum += __shfl_xor(sum, off, 64);
        if (lane == 0) out[row] = sum + bias[row];
    }
}

__global__ __launch_bounds__(256) void scores_kernel(
    const float* __restrict__ U, const float* __restrict__ Wd,
    const float* __restrict__ attn_W, const float* __restrict__ attn_b,
    float* __restrict__ scores)
{
    int t = blockIdx.x, tid = threadIdx.x;
    int wave = tid >> 6, lane = tid & 63;
    const float* Ut = U + (size_t)t * H;
    float p = 0.f;
    for (int j = tid; j < H; j += 256)
        p += tanhf(Ut[j] + Wd[j]) * attn_W[j];
#pragma unroll
    for (int off = 32; off; off >>= 1) p += __shfl_xor(p, off, 64);
    __shared__ float ws_[4];
    if (lane == 0) ws_[wave] = p;
    __syncthreads();
    if (tid == 0) scores[t] = ws_[0] + ws_[1] + ws_[2] + ws_[3] + attn_b[0];
}

__global__ __launch_bounds__(512) void softmax_kernel(
    const float* __restrict__ scores, float* __restrict__ aw,
    float* __restrict__ attn_out, float* __restrict__ din_ctx)
{
    __shared__ float red[8];
    __shared__ float m_sh, s_sh;
    int tid = threadIdx.x, wave = tid >> 6, lane = tid & 63;
    float s = scores[tid];
    float m = s;
#pragma unroll
    for (int off = 32; off; off >>= 1) m = fmaxf(m, __shfl_xor(m, off, 64));
    if (lane == 0) red[wave] = m;
    __syncthreads();
    if (tid == 0) {
        float mm = red[0];
        for (int i = 1; i < 8; i++) mm = fmaxf(mm, red[i]);
        m_sh = mm;
    }
    __syncthreads();
    float e = expf(s - m_sh);
    float p = e;
#pragma unroll
    for (int off = 32; off; off >>= 1) p += __shfl_xor(p, off, 64);
    if (lane == 0) red[wave] = p;
    __syncthreads();
    if (tid == 0) {
        float ss = 0.f;
        for (int i = 0; i < 8; i++) ss += red[i];
        s_sh = ss;
    }
    __syncthreads();
    float a = e / s_sh;
    aw[tid] = a;
    attn_out[tid] = a;
    din_ctx[tid] = 0.f; din_ctx[tid + 512] = 0.f;
    din_ctx[tid + 1024] = 0.f; din_ctx[tid + 1536] = 0.f;
}

__global__ __launch_bounds__(256) void ctx_kernel(
    const float* __restrict__ aw, const float* __restrict__ enc_out,
    float* __restrict__ din_ctx)
{
    int j = blockIdx.x * 256 + threadIdx.x;
    int t0 = blockIdx.y * 128;
    __shared__ float aw_s[128];
    if (threadIdx.x < 128) aw_s[threadIdx.x] = aw[t0 + threadIdx.x];
    __syncthreads();
    float acc = 0.f;
#pragma unroll 8
    for (int t = 0; t < 128; t++)
        acc += aw_s[t] * enc_out[(size_t)(t0 + t) * H + j];
    atomicAdd(&din_ctx[j], acc);
}

__global__ __launch_bounds__(256) void logits_kernel(
    const float* __restrict__ h2o_W, const float* __restrict__ h2o_b,
    const float* __restrict__ h2,
    const float* __restrict__ o2h_W, const float* __restrict__ o2h_b,
    float* __restrict__ out_row, float* __restrict__ din_emb)
{
    __shared__ float h_s[H];
    __shared__ float lg[OUT_];
    __shared__ float m_s, ls_s;
    __shared__ int am_s;
    int tid = threadIdx.x;
    ((float4*)h_s)[tid]       = ((const float4*)h2)[tid];
    ((float4*)h_s)[tid + 256] = ((const float4*)h2)[tid + 256];
    __syncthreads();
    int wave = tid >> 6, lane = tid & 63;
#pragma unroll
    for (int i = 0; i < 32; i++) {
        int row = i * 4 + wave;
        const float4* wr = (const float4*)(h2o_W + (size_t)row * H);
        const float4* hv = (const float4*)h_s;
        float sum = 0.f;
#pragma unroll
        for (int k = 0; k < 8; k++) {
            float4 w4 = wr[lane + 64 * k];
            float4 h4 = hv[lane + 64 * k];
            sum += w4.x * h4.x + w4.y * h4.y + w4.z * h4.z + w4.w * h4.w;
        }
#pragma unroll
        for (int off = 32; off; off >>= 1) sum += __shfl_xor(sum, off, 64);
        if (lane == 0) lg[row] = sum + h2o_b[row];
    }
    __syncthreads();
    if (tid == 0) {
        float m = lg[0]; int am = 0;
        for (int i = 1; i < OUT_; i++)
            if (lg[i] > m) { m = lg[i]; am = i; }
        float ss = 0.f;
        for (int i = 0; i < OUT_; i++) ss += expf(lg[i] - m);
        m_s = m; ls_s = logf(ss); am_s = am;
    }
    __syncthreads();
    if (tid < OUT_) out_row[tid] = (lg[tid] - m_s) - ls_s;
    int am = am_s;
    for (int j = tid; j < H; j += 256)
        din_emb[j] = o2h_W[(size_t)j * OUT_ + am] + o2h_b[j];
}

__global__ void copy_kernel(float* dst, const float* src, int n) {
    int i = blockIdx.x * blockDim.x + threadIdx.x;
    if (i < n) dst[i] = src[i];
}

extern "C" void kernel_launch(void* const* d_in, const int* in_sizes, int n_in,
                              void* d_out, int out_size, void* d_ws, size_t ws_size,
                              hipStream_t stream)
{
    const float* x     = (const float*)d_in[0];
    const float* eWih  = (const float*)d_in[1];
    const float* eWhh  = (const float*)d_in[2];
    const float* ebih  = (const float*)d_in[3];
    const float* ebhh  = (const float*)d_in[4];
    const float* dWih  = (const float*)d_in[5];
    const float* dWhh  = (const float*)d_in[6];
    const float* dbih  = (const float*)d_in[7];
    const float* dbhh  = (const float*)d_in[8];
    const float* h2oW  = (const float*)d_in[9];
    const float* h2ob  = (const float*)d_in[10];
    const float* UW    = (const float*)d_in[11];
    const float* Ub    = (const float*)d_in[12];
    const float* WW    = (const float*)d_in[13];
    const float* Wb    = (const float*)d_in[14];
    const float* attnW = (const float*)d_in[15];
    const float* attnb = (const float*)d_in[16];
    const float* o2hW  = (const float*)d_in[17];
    const float* o2hb  = (const float*)d_in[18];

    float* ws      = (float*)d_ws;
    unsigned* ctrl = (unsigned*)ws;                    // 512 slots (2KB)
    float* zrow    = ws + 512;                         // 2048 zeros (h_0)
    float* enc_out = zrow + H;                         // 512*2048
    float* gi_all  = enc_out + (size_t)T_ * H;         // 512*6144
    float* U       = gi_all + (size_t)T_ * 3 * H;      // 512*2048
    float* Wd      = U + (size_t)T_ * H;               // 2048
    float* scores  = Wd + H;                           // 512
    float* aw      = scores + T_;                      // 512
    float* din     = aw + T_;                          // 4096
    float* hd      = din + 2 * H;                      // 2*2048

    float* outs  = (float*)d_out;                      // 64*128
    float* attns = outs + STEPS * OUT_;                // 64*512

    // zero barrier slots + h0 row (d_ws is poisoned 0xAA before every call)
    hipMemsetAsync(d_ws, 0, (512 + H) * sizeof(float), stream);

    // ---- encoder ----
    gemm_abt<<<dim3(3 * H / BN, T_ / BM), 256, 0, stream>>>(
        x, eWih, ebih, gi_all, T_, 3 * H, IN_);
    enc_persistent<<<256, 512, 0, stream>>>(eWhh, ebhh, gi_all, enc_out, ctrl);

    gemm_abt<<<dim3(H / BN, T_ / BM), 256, 0, stream>>>(
        enc_out, UW, Ub, U, T_, H, H);

    // ---- decoder ----
    copy_kernel<<<8, 256, 0, stream>>>(din, o2hb, H);
    const float* h = enc_out + (size_t)(T_ - 1) * H;
    for (int s = 0; s < STEPS; s++) {
        matvec_kernel<<<64, 512, 0, stream>>>(WW, h, Wb, Wd, H, H);
        scores_kernel<<<T_, 256, 0, stream>>>(U, Wd, attnW, attnb, scores);
        softmax_kernel<<<1, 512, 0, stream>>>(scores, aw, attns + (size_t)s * T_,
                                              din + H);
        ctx_kernel<<<dim3(8, 4), 256, 0, stream>>>(aw, enc_out, din + H);
        float* hn = hd + (s & 1) * H;
        dec_gru_kernel<<<256, 512, 0, stream>>>(dWih, dWhh, dbih, dbhh, din, h, hn);
        logits_kernel<<<1, 256, 0, stream>>>(h2oW, h2ob, hn, o2hW, o2hb,
                                             outs + (size_t)s * OUT_, din);
        h = hn;
    }
}

// Round 4
// 16336.145 us; speedup vs baseline: 1.1516x; 1.0136x over previous
//
#include <hip/hip_runtime.h>
#include <math.h>

// Sizes fixed by setup_inputs(): H=2048, IN=128, OUT=128, T=512, STEPS=64
#define H    2048
#define IN_  128
#define OUT_ 128
#define T_   512
#define STEPS 64

// ---------------------------------------------------------------------------
// Generic tiled GEMM: C[M,N] = A[M,K] @ B[N,K]^T + bias[N]   (all row-major)
// ---------------------------------------------------------------------------
#define BM 64
#define BN 64
#define BK 16
__global__ __launch_bounds__(256) void gemm_abt(
    const float* __restrict__ A, const float* __restrict__ B,
    const float* __restrict__ bias, float* __restrict__ C,
    int M, int N, int K)
{
    __shared__ float As[BM][BK + 1];
    __shared__ float Bs[BN][BK + 1];
    int tid = threadIdx.x;
    int m0 = blockIdx.y * BM, n0 = blockIdx.x * BN;
    int ty = tid / 16, tx = tid % 16;
    float acc[4][4] = {};
    int r = tid >> 2, q = tid & 3;
    for (int k0 = 0; k0 < K; k0 += BK) {
        float4 a4 = *(const float4*)(A + (size_t)(m0 + r) * K + k0 + q * 4);
        As[r][q * 4 + 0] = a4.x; As[r][q * 4 + 1] = a4.y;
        As[r][q * 4 + 2] = a4.z; As[r][q * 4 + 3] = a4.w;
        float4 b4 = *(const float4*)(B + (size_t)(n0 + r) * K + k0 + q * 4);
        Bs[r][q * 4 + 0] = b4.x; Bs[r][q * 4 + 1] = b4.y;
        Bs[r][q * 4 + 2] = b4.z; Bs[r][q * 4 + 3] = b4.w;
        __syncthreads();
#pragma unroll
        for (int kk = 0; kk < BK; kk++) {
            float a[4], b[4];
#pragma unroll
            for (int i = 0; i < 4; i++) a[i] = As[ty * 4 + i][kk];
#pragma unroll
            for (int j = 0; j < 4; j++) b[j] = Bs[tx * 4 + j][kk];
#pragma unroll
            for (int i = 0; i < 4; i++)
#pragma unroll
                for (int j = 0; j < 4; j++) acc[i][j] += a[i] * b[j];
        }
        __syncthreads();
    }
#pragma unroll
    for (int i = 0; i < 4; i++)
#pragma unroll
        for (int j = 0; j < 4; j++)
            C[(size_t)(m0 + ty * 4 + i) * N + n0 + tx * 4 + j] =
                acc[i][j] + bias[n0 + tx * 4 + j];
}

// ---------------------------------------------------------------------------
// Persistent encoder: 256 blocks x 512 threads, 1 block/CU.
// Block b owns hidden units j0=8b..j0+7 (24 rows of Whh register-resident).
//
// Barrier v3 (two-level flag, minimal pollers):
//   R2 lesson: 256-deep fetch_add chain is serial. R3 lesson: 65K threads
//   polling device-scope atomics congest the coherence fabric and delay the
//   releasing stores (~25us/step). v3: arrival slots (parallel stores), but
//   ONLY block 0 polls the slots (256 threads, 1 slot each); it then raises
//   a single generation flag ctrl[256]; other blocks poll that flag with ONE
//   thread each + s_sleep backoff. ~511 pollers total instead of 65536.
// ---------------------------------------------------------------------------
__global__ __launch_bounds__(512, 2) void enc_persistent(
    const float* __restrict__ Whh, const float* __restrict__ bhh,
    const float* __restrict__ gi_all, float* __restrict__ enc_out,
    unsigned* __restrict__ ctrl)
{
    __shared__ float h_s[H];
    __shared__ float red_s[24];
    const int tid = threadIdx.x;
    const int wv = tid >> 6, ln = tid & 63;
    const int j0 = blockIdx.x * 8;

    // ---- one-time: weights -> registers (coalesced float4 loads) ----
    float4 wreg[3][8];
    float bias[3];
    int sidx[3];
#pragma unroll
    for (int i = 0; i < 3; i++) {
        int ridx = wv * 3 + i;            // 0..23
        int u = ridx & 7, g = ridx >> 3;  // gate 0=r,1=z,2=n
        int row = g * H + j0 + u;
        const float4* wr = (const float4*)(Whh + (size_t)row * H);
#pragma unroll
        for (int m = 0; m < 8; m++) wreg[i][m] = wr[ln + (m << 6)];
        bias[i] = bhh[row];
        sidx[i] = g * 8 + u;
    }

    for (int t = 0; t < T_; t++) {
        // h_{t-1} -> LDS (t=0 reads the zero row at enc_out[-H])
        const float4* hprev = (const float4*)(enc_out + (size_t)(t - 1) * H);
        ((float4*)h_s)[tid] = hprev[tid];
        float ir = 0.f, iz = 0.f, inn = 0.f;
        if (tid < 8) {
            const float* gi = gi_all + (size_t)t * 3 * H;
            ir  = gi[j0 + tid];
            iz  = gi[H + j0 + tid];
            inn = gi[2 * H + j0 + tid];
        }
        __syncthreads();

        float s0 = 0.f, s1 = 0.f, s2 = 0.f;
#pragma unroll
        for (int m = 0; m < 8; m++) {
            float4 h4 = ((const float4*)h_s)[ln + (m << 6)];
            s0 += wreg[0][m].x * h4.x + wreg[0][m].y * h4.y +
                  wreg[0][m].z * h4.z + wreg[0][m].w * h4.w;
            s1 += wreg[1][m].x * h4.x + wreg[1][m].y * h4.y +
                  wreg[1][m].z * h4.z + wreg[1][m].w * h4.w;
            s2 += wreg[2][m].x * h4.x + wreg[2][m].y * h4.y +
                  wreg[2][m].z * h4.z + wreg[2][m].w * h4.w;
        }
#pragma unroll
        for (int off = 32; off; off >>= 1) {
            s0 += __shfl_xor(s0, off, 64);
            s1 += __shfl_xor(s1, off, 64);
            s2 += __shfl_xor(s2, off, 64);
        }
        if (ln == 0) {
            red_s[sidx[0]] = s0 + bias[0];
            red_s[sidx[1]] = s1 + bias[1];
            red_s[sidx[2]] = s2 + bias[2];
        }
        __syncthreads();

        if (tid < 8) {
            float hr = red_s[tid], hz = red_s[8 + tid], hn = red_s[16 + tid];
            float rg = 1.f / (1.f + expf(-(ir + hr)));
            float zg = 1.f / (1.f + expf(-(iz + hz)));
            float ng = tanhf(inn + rg * hn);
            enc_out[(size_t)t * H + j0 + tid] =
                (1.f - zg) * ng + zg * h_s[j0 + tid];
        }

        // ---- barrier v3 ----
        __syncthreads();
        if (tid == 0) {
            __builtin_amdgcn_fence(__ATOMIC_RELEASE, "agent");
            __hip_atomic_store(&ctrl[blockIdx.x], (unsigned)(t + 1),
                               __ATOMIC_RELAXED, __HIP_MEMORY_SCOPE_AGENT);
        }
        if (blockIdx.x == 0) {
            if (tid < 256) {
                while (__hip_atomic_load(&ctrl[tid], __ATOMIC_RELAXED,
                                         __HIP_MEMORY_SCOPE_AGENT) <
                       (unsigned)(t + 1))
                    __builtin_amdgcn_s_sleep(1);
            }
            __syncthreads();
            if (tid == 0)
                __hip_atomic_store(&ctrl[256], (unsigned)(t + 1),
                                   __ATOMIC_RELAXED, __HIP_MEMORY_SCOPE_AGENT);
        } else {
            if (tid == 0) {
                while (__hip_atomic_load(&ctrl[256], __ATOMIC_RELAXED,
                                         __HIP_MEMORY_SCOPE_AGENT) <
                       (unsigned)(t + 1))
                    __builtin_amdgcn_s_sleep(4);
            }
        }
        __builtin_amdgcn_fence(__ATOMIC_ACQUIRE, "agent");
        __syncthreads();
    }
}

// ---------------------------------------------------------------------------
// Decoder GRU step (unchanged).
// ---------------------------------------------------------------------------
__global__ __launch_bounds__(512) void dec_gru_kernel(
    const float* __restrict__ Wih, const float* __restrict__ Whh,
    const float* __restrict__ bih, const float* __restrict__ bhh,
    const float* __restrict__ din, const float* __restrict__ h_prev,
    float* __restrict__ h_out)
{
    __shared__ float d_s[2 * H];
    __shared__ float h_s[H];
    __shared__ float red_s[48];
    int tid = threadIdx.x;
    ((float4*)d_s)[tid]       = ((const float4*)din)[tid];
    ((float4*)d_s)[tid + 512] = ((const float4*)din)[tid + 512];
    ((float4*)h_s)[tid]       = ((const float4*)h_prev)[tid];
    __syncthreads();
    int wave = tid >> 6, lane = tid & 63;
    int j0 = blockIdx.x * 8;
#pragma unroll
    for (int i = 0; i < 6; i++) {
        int ridx = i * 8 + wave;
        int big = (ridx < 24);
        int rr = big ? ridx : ridx - 24;
        int u = rr & 7, g = rr >> 3;
        int row = g * H + j0 + u;
        float sum = 0.f, bs;
        if (big) {
            const float4* wr = (const float4*)(Wih + (size_t)row * (2 * H));
            const float4* dv = (const float4*)d_s;
#pragma unroll
            for (int k = 0; k < 16; k++) {
                float4 w4 = wr[lane + 64 * k];
                float4 v4 = dv[lane + 64 * k];
                sum += w4.x * v4.x + w4.y * v4.y + w4.z * v4.z + w4.w * v4.w;
            }
            bs = bih[row];
        } else {
            const float4* wr = (const float4*)(Whh + (size_t)row * H);
            const float4* hv = (const float4*)h_s;
#pragma unroll
            for (int k = 0; k < 8; k++) {
                float4 w4 = wr[lane + 64 * k];
                float4 h4 = hv[lane + 64 * k];
                sum += w4.x * h4.x + w4.y * h4.y + w4.z * h4.z + w4.w * h4.w;
            }
            bs = bhh[row];
        }
#pragma unroll
        for (int off = 32; off; off >>= 1) sum += __shfl_xor(sum, off, 64);
        if (lane == 0) red_s[ridx] = sum + bs;
    }
    __syncthreads();
    if (tid < 8) {
        int j = j0 + tid;
        float ir = red_s[tid], iz = red_s[8 + tid], inn = red_s[16 + tid];
        float hr = red_s[24 + tid], hz = red_s[32 + tid], hn = red_s[40 + tid];
        float rg = 1.f / (1.f + expf(-(ir + hr)));
        float zg = 1.f / (1.f + expf(-(iz + hz)));
        float ng = tanhf(inn + rg * hn);
        h_out[j] = (1.f - zg) * ng + zg * h_s[j];
    }
}

__global__ __launch_bounds__(512) void matvec_kernel(
    const float* __restrict__ W, const float* __restrict__ v,
    const float* __restrict__ bias, float* __restrict__ out,
    int nrows, int K)
{
    __shared__ float v_s[4096];
    int tid = threadIdx.x;
    for (int i = tid; i < (K >> 2); i += blockDim.x)
        ((float4*)v_s)[i] = ((const float4*)v)[i];
    __syncthreads();
    int lane = tid & 63;
    int gw = (blockIdx.x * blockDim.x + tid) >> 6;
    int nw = (gridDim.x * blockDim.x) >> 6;
    int kq = K >> 2;
    for (int row = gw; row < nrows; row += nw) {
        const float4* wr = (const float4*)(W + (size_t)row * K);
        const float4* vv = (const float4*)v_s;
        float sum = 0.f;
        for (int k = lane; k < kq; k += 64) {
            float4 w4 = wr[k]; float4 h4 = vv[k];
            sum += w4.x * h4.x + w4.y * h4.y + w4.z * h4.z + w4.w * h4.w;
        }
#pragma unroll
        for (int off = 32; off; off >>= 1) sum += __shfl_xor(sum, off, 64);
        if (lane == 0) out[row] = sum + bias[row];
    }
}

__global__ __launch_bounds__(256) void scores_kernel(
    const float* __restrict__ U, const float* __restrict__ Wd,
    const float* __restrict__ attn_W, const float* __restrict__ attn_b,
    float* __restrict__ scores)
{
    int t = blockIdx.x, tid = threadIdx.x;
    int wave = tid >> 6, lane = tid & 63;
    const float* Ut = U + (size_t)t * H;
    float p = 0.f;
    for (int j = tid; j < H; j += 256)
        p += tanhf(Ut[j] + Wd[j]) * attn_W[j];
#pragma unroll
    for (int off = 32; off; off >>= 1) p += __shfl_xor(p, off, 64);
    __shared__ float ws_[4];
    if (lane == 0) ws_[wave] = p;
    __syncthreads();
    if (tid == 0) scores[t] = ws_[0] + ws_[1] + ws_[2] + ws_[3] + attn_b[0];
}

__global__ __launch_bounds__(512) void softmax_kernel(
    const float* __restrict__ scores, float* __restrict__ aw,
    float* __restrict__ attn_out, float* __restrict__ din_ctx)
{
    __shared__ float red[8];
    __shared__ float m_sh, s_sh;
    int tid = threadIdx.x, wave = tid >> 6, lane = tid & 63;
    float s = scores[tid];
    float m = s;
#pragma unroll
    for (int off = 32; off; off >>= 1) m = fmaxf(m, __shfl_xor(m, off, 64));
    if (lane == 0) red[wave] = m;
    __syncthreads();
    if (tid == 0) {
        float mm = red[0];
        for (int i = 1; i < 8; i++) mm = fmaxf(mm, red[i]);
        m_sh = mm;
    }
    __syncthreads();
    float e = expf(s - m_sh);
    float p = e;
#pragma unroll
    for (int off = 32; off; off >>= 1) p += __shfl_xor(p, off, 64);
    if (lane == 0) red[wave] = p;
    __syncthreads();
    if (tid == 0) {
        float ss = 0.f;
        for (int i = 0; i < 8; i++) ss += red[i];
        s_sh = ss;
    }
    __syncthreads();
    float a = e / s_sh;
    aw[tid] = a;
    attn_out[tid] = a;
    din_ctx[tid] = 0.f; din_ctx[tid + 512] = 0.f;
    din_ctx[tid + 1024] = 0.f; din_ctx[tid + 1536] = 0.f;
}

__global__ __launch_bounds__(256) void ctx_kernel(
    const float* __restrict__ aw, const float* __restrict__ enc_out,
    float* __restrict__ din_ctx)
{
    int j = blockIdx.x * 256 + threadIdx.x;
    int t0 = blockIdx.y * 128;
    __shared__ float aw_s[128];
    if (threadIdx.x < 128) aw_s[threadIdx.x] = aw[t0 + threadIdx.x];
    __syncthreads();
    float acc = 0.f;
#pragma unroll 8
    for (int t = 0; t < 128; t++)
        acc += aw_s[t] * enc_out[(size_t)(t0 + t) * H + j];
    atomicAdd(&din_ctx[j], acc);
}

__global__ __launch_bounds__(256) void logits_kernel(
    const float* __restrict__ h2o_W, const float* __restrict__ h2o_b,
    const float* __restrict__ h2,
    const float* __restrict__ o2h_W, const float* __restrict__ o2h_b,
    float* __restrict__ out_row, float* __restrict__ din_emb)
{
    __shared__ float h_s[H];
    __shared__ float lg[OUT_];
    __shared__ float m_s, ls_s;
    __shared__ int am_s;
    int tid = threadIdx.x;
    ((float4*)h_s)[tid]       = ((const float4*)h2)[tid];
    ((float4*)h_s)[tid + 256] = ((const float4*)h2)[tid + 256];
    __syncthreads();
    int wave = tid >> 6, lane = tid & 63;
#pragma unroll
    for (int i = 0; i < 32; i++) {
        int row = i * 4 + wave;
        const float4* wr = (const float4*)(h2o_W + (size_t)row * H);
        const float4* hv = (const float4*)h_s;
        float sum = 0.f;
#pragma unroll
        for (int k = 0; k < 8; k++) {
            float4 w4 = wr[lane + 64 * k];
            float4 h4 = hv[lane + 64 * k];
            sum += w4.x * h4.x + w4.y * h4.y + w4.z * h4.z + w4.w * h4.w;
        }
#pragma unroll
        for (int off = 32; off; off >>= 1) sum += __shfl_xor(sum, off, 64);
        if (lane == 0) lg[row] = sum + h2o_b[row];
    }
    __syncthreads();
    if (tid == 0) {
        float m = lg[0]; int am = 0;
        for (int i = 1; i < OUT_; i++)
            if (lg[i] > m) { m = lg[i]; am = i; }
        float ss = 0.f;
        for (int i = 0; i < OUT_; i++) ss += expf(lg[i] - m);
        m_s = m; ls_s = logf(ss); am_s = am;
    }
    __syncthreads();
    if (tid < OUT_) out_row[tid] = (lg[tid] - m_s) - ls_s;
    int am = am_s;
    for (int j = tid; j < H; j += 256)
        din_emb[j] = o2h_W[(size_t)j * OUT_ + am] + o2h_b[j];
}

__global__ void copy_kernel(float* dst, const float* src, int n) {
    int i = blockIdx.x * blockDim.x + threadIdx.x;
    if (i < n) dst[i] = src[i];
}

extern "C" void kernel_launch(void* const* d_in, const int* in_sizes, int n_in,
                              void* d_out, int out_size, void* d_ws, size_t ws_size,
                              hipStream_t stream)
{
    const float* x     = (const float*)d_in[0];
    const float* eWih  = (const float*)d_in[1];
    const float* eWhh  = (const float*)d_in[2];
    const float* ebih  = (const float*)d_in[3];
    const float* ebhh  = (const float*)d_in[4];
    const float* dWih  = (const float*)d_in[5];
    const float* dWhh  = (const float*)d_in[6];
    const float* dbih  = (const float*)d_in[7];
    const float* dbhh  = (const float*)d_in[8];
    const float* h2oW  = (const float*)d_in[9];
    const float* h2ob  = (const float*)d_in[10];
    const float* UW    = (const float*)d_in[11];
    const float* Ub    = (const float*)d_in[12];
    const float* WW    = (const float*)d_in[13];
    const float* Wb    = (const float*)d_in[14];
    const float* attnW = (const float*)d_in[15];
    const float* attnb = (const float*)d_in[16];
    const float* o2hW  = (const float*)d_in[17];
    const float* o2hb  = (const float*)d_in[18];

    float* ws      = (float*)d_ws;
    unsigned* ctrl = (unsigned*)ws;                    // 512 slots (2KB); [256]=flag
    float* zrow    = ws + 512;                         // 2048 zeros (h_0)
    float* enc_out = zrow + H;                         // 512*2048
    float* gi_all  = enc_out + (size_t)T_ * H;         // 512*6144
    float* U       = gi_all + (size_t)T_ * 3 * H;      // 512*2048
    float* Wd      = U + (size_t)T_ * H;               // 2048
    float* scores  = Wd + H;                           // 512
    float* aw      = scores + T_;                      // 512
    float* din     = aw + T_;                          // 4096
    float* hd      = din + 2 * H;                      // 2*2048

    float* outs  = (float*)d_out;                      // 64*128
    float* attns = outs + STEPS * OUT_;                // 64*512

    // zero barrier slots + h0 row (d_ws is poisoned 0xAA before every call)
    hipMemsetAsync(d_ws, 0, (512 + H) * sizeof(float), stream);

    // ---- encoder ----
    gemm_abt<<<dim3(3 * H / BN, T_ / BM), 256, 0, stream>>>(
        x, eWih, ebih, gi_all, T_, 3 * H, IN_);
    enc_persistent<<<256, 512, 0, stream>>>(eWhh, ebhh, gi_all, enc_out, ctrl);

    gemm_abt<<<dim3(H / BN, T_ / BM), 256, 0, stream>>>(
        enc_out, UW, Ub, U, T_, H, H);

    // ---- decoder ----
    copy_kernel<<<8, 256, 0, stream>>>(din, o2hb, H);
    const float* h = enc_out + (size_t)(T_ - 1) * H;
    for (int s = 0; s < STEPS; s++) {
        matvec_kernel<<<64, 512, 0, stream>>>(WW, h, Wb, Wd, H, H);
        scores_kernel<<<T_, 256, 0, stream>>>(U, Wd, attnW, attnb, scores);
        softmax_kernel<<<1, 512, 0, stream>>>(scores, aw, attns + (size_t)s * T_,
                                              din + H);
        ctx_kernel<<<dim3(8, 4), 256, 0, stream>>>(aw, enc_out, din + H);
        float* hn = hd + (s & 1) * H;
        dec_gru_kernel<<<256, 512, 0, stream>>>(dWih, dWhh, dbih, dbhh, din, h, hn);
        logits_kernel<<<1, 256, 0, stream>>>(h2oW, h2ob, hn, o2hW, o2hb,
                                             outs + (size_t)s * OUT_, din);
        h = hn;
    }
}

// Round 5
// 16196.581 us; speedup vs baseline: 1.1615x; 1.0086x over previous
//
#include <hip/hip_runtime.h>
#include <math.h>

// Sizes fixed by setup_inputs(): H=2048, IN=128, OUT=128, T=512, STEPS=64
#define H    2048
#define IN_  128
#define OUT_ 128
#define T_   512
#define STEPS 64

// ---------------------------------------------------------------------------
// Generic tiled GEMM: C[M,N] = A[M,K] @ B[N,K]^T + bias[N]   (all row-major)
// ---------------------------------------------------------------------------
#define BM 64
#define BN 64
#define BK 16
__global__ __launch_bounds__(256) void gemm_abt(
    const float* __restrict__ A, const float* __restrict__ B,
    const float* __restrict__ bias, float* __restrict__ C,
    int M, int N, int K)
{
    __shared__ float As[BM][BK + 1];
    __shared__ float Bs[BN][BK + 1];
    int tid = threadIdx.x;
    int m0 = blockIdx.y * BM, n0 = blockIdx.x * BN;
    int ty = tid / 16, tx = tid % 16;
    float acc[4][4] = {};
    int r = tid >> 2, q = tid & 3;
    for (int k0 = 0; k0 < K; k0 += BK) {
        float4 a4 = *(const float4*)(A + (size_t)(m0 + r) * K + k0 + q * 4);
        As[r][q * 4 + 0] = a4.x; As[r][q * 4 + 1] = a4.y;
        As[r][q * 4 + 2] = a4.z; As[r][q * 4 + 3] = a4.w;
        float4 b4 = *(const float4*)(B + (size_t)(n0 + r) * K + k0 + q * 4);
        Bs[r][q * 4 + 0] = b4.x; Bs[r][q * 4 + 1] = b4.y;
        Bs[r][q * 4 + 2] = b4.z; Bs[r][q * 4 + 3] = b4.w;
        __syncthreads();
#pragma unroll
        for (int kk = 0; kk < BK; kk++) {
            float a[4], b[4];
#pragma unroll
            for (int i = 0; i < 4; i++) a[i] = As[ty * 4 + i][kk];
#pragma unroll
            for (int j = 0; j < 4; j++) b[j] = Bs[tx * 4 + j][kk];
#pragma unroll
            for (int i = 0; i < 4; i++)
#pragma unroll
                for (int j = 0; j < 4; j++) acc[i][j] += a[i] * b[j];
        }
        __syncthreads();
    }
#pragma unroll
    for (int i = 0; i < 4; i++)
#pragma unroll
        for (int j = 0; j < 4; j++)
            C[(size_t)(m0 + ty * 4 + i) * N + n0 + tx * 4 + j] =
                acc[i][j] + bias[n0 + tx * 4 + j];
}

// ---------------------------------------------------------------------------
// Persistent encoder: 256 blocks x 512 threads, 1 block/CU.
// Block b owns hidden units j0=8b..j0+7 (24 rows of Whh register-resident:
// wreg[3][8] float4 = 96 VGPRs/lane).
//
// __launch_bounds__(512, 1): R4 lesson — (512,2) capped VGPRs at 128/lane,
// which spilled the 96-VGPR weight array to scratch; every step re-read
// ~50 MB of spilled weights (≈25us/step), masking all barrier variants.
// Grid == 256 == CU count, so 1 block/CU is what we want anyway; the 256
// VGPR budget keeps wreg in registers.
//
// Barrier v3 (two-level flag): arrival slots (parallel relaxed stores);
// block 0 polls slots (256 threads, 1 each), raises generation flag
// ctrl[256]; other blocks poll the flag with one thread each.
// ---------------------------------------------------------------------------
__global__ __launch_bounds__(512, 1) void enc_persistent(
    const float* __restrict__ Whh, const float* __restrict__ bhh,
    const float* __restrict__ gi_all, float* __restrict__ enc_out,
    unsigned* __restrict__ ctrl)
{
    __shared__ float h_s[H];
    __shared__ float red_s[24];
    const int tid = threadIdx.x;
    const int wv = tid >> 6, ln = tid & 63;
    const int j0 = blockIdx.x * 8;

    // ---- one-time: weights -> registers (coalesced float4 loads) ----
    float4 wreg[3][8];
    float bias[3];
    int sidx[3];
#pragma unroll
    for (int i = 0; i < 3; i++) {
        int ridx = wv * 3 + i;            // 0..23
        int u = ridx & 7, g = ridx >> 3;  // gate 0=r,1=z,2=n
        int row = g * H + j0 + u;
        const float4* wr = (const float4*)(Whh + (size_t)row * H);
#pragma unroll
        for (int m = 0; m < 8; m++) wreg[i][m] = wr[ln + (m << 6)];
        bias[i] = bhh[row];
        sidx[i] = g * 8 + u;
    }

    for (int t = 0; t < T_; t++) {
        // h_{t-1} -> LDS (t=0 reads the zero row at enc_out[-H])
        const float4* hprev = (const float4*)(enc_out + (size_t)(t - 1) * H);
        ((float4*)h_s)[tid] = hprev[tid];
        float ir = 0.f, iz = 0.f, inn = 0.f;
        if (tid < 8) {
            const float* gi = gi_all + (size_t)t * 3 * H;
            ir  = gi[j0 + tid];
            iz  = gi[H + j0 + tid];
            inn = gi[2 * H + j0 + tid];
        }
        __syncthreads();

        float s0 = 0.f, s1 = 0.f, s2 = 0.f;
#pragma unroll
        for (int m = 0; m < 8; m++) {
            float4 h4 = ((const float4*)h_s)[ln + (m << 6)];
            s0 += wreg[0][m].x * h4.x + wreg[0][m].y * h4.y +
                  wreg[0][m].z * h4.z + wreg[0][m].w * h4.w;
            s1 += wreg[1][m].x * h4.x + wreg[1][m].y * h4.y +
                  wreg[1][m].z * h4.z + wreg[1][m].w * h4.w;
            s2 += wreg[2][m].x * h4.x + wreg[2][m].y * h4.y +
                  wreg[2][m].z * h4.z + wreg[2][m].w * h4.w;
        }
#pragma unroll
        for (int off = 32; off; off >>= 1) {
            s0 += __shfl_xor(s0, off, 64);
            s1 += __shfl_xor(s1, off, 64);
            s2 += __shfl_xor(s2, off, 64);
        }
        if (ln == 0) {
            red_s[sidx[0]] = s0 + bias[0];
            red_s[sidx[1]] = s1 + bias[1];
            red_s[sidx[2]] = s2 + bias[2];
        }
        __syncthreads();

        if (tid < 8) {
            float hr = red_s[tid], hz = red_s[8 + tid], hn = red_s[16 + tid];
            float rg = 1.f / (1.f + expf(-(ir + hr)));
            float zg = 1.f / (1.f + expf(-(iz + hz)));
            float ng = tanhf(inn + rg * hn);
            enc_out[(size_t)t * H + j0 + tid] =
                (1.f - zg) * ng + zg * h_s[j0 + tid];
        }

        // ---- barrier v3 ----
        __syncthreads();
        if (tid == 0) {
            __builtin_amdgcn_fence(__ATOMIC_RELEASE, "agent");
            __hip_atomic_store(&ctrl[blockIdx.x], (unsigned)(t + 1),
                               __ATOMIC_RELAXED, __HIP_MEMORY_SCOPE_AGENT);
        }
        if (blockIdx.x == 0) {
            if (tid < 256) {
                while (__hip_atomic_load(&ctrl[tid], __ATOMIC_RELAXED,
                                         __HIP_MEMORY_SCOPE_AGENT) <
                       (unsigned)(t + 1))
                    __builtin_amdgcn_s_sleep(1);
            }
            __syncthreads();
            if (tid == 0)
                __hip_atomic_store(&ctrl[256], (unsigned)(t + 1),
                                   __ATOMIC_RELAXED, __HIP_MEMORY_SCOPE_AGENT);
        } else {
            if (tid == 0) {
                while (__hip_atomic_load(&ctrl[256], __ATOMIC_RELAXED,
                                         __HIP_MEMORY_SCOPE_AGENT) <
                       (unsigned)(t + 1))
                    __builtin_amdgcn_s_sleep(4);
            }
        }
        __builtin_amdgcn_fence(__ATOMIC_ACQUIRE, "agent");
        __syncthreads();
    }
}

// ---------------------------------------------------------------------------
// Decoder GRU step (unchanged).
// ---------------------------------------------------------------------------
__global__ __launch_bounds__(512) void dec_gru_kernel(
    const float* __restrict__ Wih, const float* __restrict__ Whh,
    const float* __restrict__ bih, const float* __restrict__ bhh,
    const float* __restrict__ din, const float* __restrict__ h_prev,
    float* __restrict__ h_out)
{
    __shared__ float d_s[2 * H];
    __shared__ float h_s[H];
    __shared__ float red_s[48];
    int tid = threadIdx.x;
    ((float4*)d_s)[tid]       = ((const float4*)din)[tid];
    ((float4*)d_s)[tid + 512] = ((const float4*)din)[tid + 512];
    ((float4*)h_s)[tid]       = ((const float4*)h_prev)[tid];
    __syncthreads();
    int wave = tid >> 6, lane = tid & 63;
    int j0 = blockIdx.x * 8;
#pragma unroll
    for (int i = 0; i < 6; i++) {
        int ridx = i * 8 + wave;
        int big = (ridx < 24);
        int rr = big ? ridx : ridx - 24;
        int u = rr & 7, g = rr >> 3;
        int row = g * H + j0 + u;
        float sum = 0.f, bs;
        if (big) {
            const float4* wr = (const float4*)(Wih + (size_t)row * (2 * H));
            const float4* dv = (const float4*)d_s;
#pragma unroll
            for (int k = 0; k < 16; k++) {
                float4 w4 = wr[lane + 64 * k];
                float4 v4 = dv[lane + 64 * k];
                sum += w4.x * v4.x + w4.y * v4.y + w4.z * v4.z + w4.w * v4.w;
            }
            bs = bih[row];
        } else {
            const float4* wr = (const float4*)(Whh + (size_t)row * H);
            const float4* hv = (const float4*)h_s;
#pragma unroll
            for (int k = 0; k < 8; k++) {
                float4 w4 = wr[lane + 64 * k];
                float4 h4 = hv[lane + 64 * k];
                sum += w4.x * h4.x + w4.y * h4.y + w4.z * h4.z + w4.w * h4.w;
            }
            bs = bhh[row];
        }
#pragma unroll
        for (int off = 32; off; off >>= 1) sum += __shfl_xor(sum, off, 64);
        if (lane == 0) red_s[ridx] = sum + bs;
    }
    __syncthreads();
    if (tid < 8) {
        int j = j0 + tid;
        float ir = red_s[tid], iz = red_s[8 + tid], inn = red_s[16 + tid];
        float hr = red_s[24 + tid], hz = red_s[32 + tid], hn = red_s[40 + tid];
        float rg = 1.f / (1.f + expf(-(ir + hr)));
        float zg = 1.f / (1.f + expf(-(iz + hz)));
        float ng = tanhf(inn + rg * hn);
        h_out[j] = (1.f - zg) * ng + zg * h_s[j];
    }
}

__global__ __launch_bounds__(512) void matvec_kernel(
    const float* __restrict__ W, const float* __restrict__ v,
    const float* __restrict__ bias, float* __restrict__ out,
    int nrows, int K)
{
    __shared__ float v_s[4096];
    int tid = threadIdx.x;
    for (int i = tid; i < (K >> 2); i += blockDim.x)
        ((float4*)v_s)[i] = ((const float4*)v)[i];
    __syncthreads();
    int lane = tid & 63;
    int gw = (blockIdx.x * blockDim.x + tid) >> 6;
    int nw = (gridDim.x * blockDim.x) >> 6;
    int kq = K >> 2;
    for (int row = gw; row < nrows; row += nw) {
        const float4* wr = (const float4*)(W + (size_t)row * K);
        const float4* vv = (const float4*)v_s;
        float sum = 0.f;
        for (int k = lane; k < kq; k += 64) {
            float4 w4 = wr[k]; float4 h4 = vv[k];
            sum += w4.x * h4.x + w4.y * h4.y + w4.z * h4.z + w4.w * h4.w;
        }
#pragma unroll
        for (int off = 32; off; off >>= 1) sum += __shfl_xor(sum, off, 64);
        if (lane == 0) out[row] = sum + bias[row];
    }
}

__global__ __launch_bounds__(256) void scores_kernel(
    const float* __restrict__ U, const float* __restrict__ Wd,
    const float* __restrict__ attn_W, const float* __restrict__ attn_b,
    float* __restrict__ scores)
{
    int t = blockIdx.x, tid = threadIdx.x;
    int wave = tid >> 6, lane = tid & 63;
    const float* Ut = U + (size_t)t * H;
    float p = 0.f;
    for (int j = tid; j < H; j += 256)
        p += tanhf(Ut[j] + Wd[j]) * attn_W[j];
#pragma unroll
    for (int off = 32; off; off >>= 1) p += __shfl_xor(p, off, 64);
    __shared__ float ws_[4];
    if (lane == 0) ws_[wave] = p;
    __syncthreads();
    if (tid == 0) scores[t] = ws_[0] + ws_[1] + ws_[2] + ws_[3] + attn_b[0];
}

__global__ __launch_bounds__(512) void softmax_kernel(
    const float* __restrict__ scores, float* __restrict__ aw,
    float* __restrict__ attn_out, float* __restrict__ din_ctx)
{
    __shared__ float red[8];
    __shared__ float m_sh, s_sh;
    int tid = threadIdx.x, wave = tid >> 6, lane = tid & 63;
    float s = scores[tid];
    float m = s;
#pragma unroll
    for (int off = 32; off; off >>= 1) m = fmaxf(m, __shfl_xor(m, off, 64));
    if (lane == 0) red[wave] = m;
    __syncthreads();
    if (tid == 0) {
        float mm = red[0];
        for (int i = 1; i < 8; i++) mm = fmaxf(mm, red[i]);
        m_sh = mm;
    }
    __syncthreads();
    float e = expf(s - m_sh);
    float p = e;
#pragma unroll
    for (int off = 32; off; off >>= 1) p += __shfl_xor(p, off, 64);
    if (lane == 0) red[wave] = p;
    __syncthreads();
    if (tid == 0) {
        float ss = 0.f;
        for (int i = 0; i < 8; i++) ss += red[i];
        s_sh = ss;
    }
    __syncthreads();
    float a = e / s_sh;
    aw[tid] = a;
    attn_out[tid] = a;
    din_ctx[tid] = 0.f; din_ctx[tid + 512] = 0.f;
    din_ctx[tid + 1024] = 0.f; din_ctx[tid + 1536] = 0.f;
}

__global__ __launch_bounds__(256) void ctx_kernel(
    const float* __restrict__ aw, const float* __restrict__ enc_out,
    float* __restrict__ din_ctx)
{
    int j = blockIdx.x * 256 + threadIdx.x;
    int t0 = blockIdx.y * 128;
    __shared__ float aw_s[128];
    if (threadIdx.x < 128) aw_s[threadIdx.x] = aw[t0 + threadIdx.x];
    __syncthreads();
    float acc = 0.f;
#pragma unroll 8
    for (int t = 0; t < 128; t++)
        acc += aw_s[t] * enc_out[(size_t)(t0 + t) * H + j];
    atomicAdd(&din_ctx[j], acc);
}

__global__ __launch_bounds__(256) void logits_kernel(
    const float* __restrict__ h2o_W, const float* __restrict__ h2o_b,
    const float* __restrict__ h2,
    const float* __restrict__ o2h_W, const float* __restrict__ o2h_b,
    float* __restrict__ out_row, float* __restrict__ din_emb)
{
    __shared__ float h_s[H];
    __shared__ float lg[OUT_];
    __shared__ float m_s, ls_s;
    __shared__ int am_s;
    int tid = threadIdx.x;
    ((float4*)h_s)[tid]       = ((const float4*)h2)[tid];
    ((float4*)h_s)[tid + 256] = ((const float4*)h2)[tid + 256];
    __syncthreads();
    int wave = tid >> 6, lane = tid & 63;
#pragma unroll
    for (int i = 0; i < 32; i++) {
        int row = i * 4 + wave;
        const float4* wr = (const float4*)(h2o_W + (size_t)row * H);
        const float4* hv = (const float4*)h_s;
        float sum = 0.f;
#pragma unroll
        for (int k = 0; k < 8; k++) {
            float4 w4 = wr[lane + 64 * k];
            float4 h4 = hv[lane + 64 * k];
            sum += w4.x * h4.x + w4.y * h4.y + w4.z * h4.z + w4.w * h4.w;
        }
#pragma unroll
        for (int off = 32; off; off >>= 1) sum += __shfl_xor(sum, off, 64);
        if (lane == 0) lg[row] = sum + h2o_b[row];
    }
    __syncthreads();
    if (tid == 0) {
        float m = lg[0]; int am = 0;
        for (int i = 1; i < OUT_; i++)
            if (lg[i] > m) { m = lg[i]; am = i; }
        float ss = 0.f;
        for (int i = 0; i < OUT_; i++) ss += expf(lg[i] - m);
        m_s = m; ls_s = logf(ss); am_s = am;
    }
    __syncthreads();
    if (tid < OUT_) out_row[tid] = (lg[tid] - m_s) - ls_s;
    int am = am_s;
    for (int j = tid; j < H; j += 256)
        din_emb[j] = o2h_W[(size_t)j * OUT_ + am] + o2h_b[j];
}

__global__ void copy_kernel(float* dst, const float* src, int n) {
    int i = blockIdx.x * blockDim.x + threadIdx.x;
    if (i < n) dst[i] = src[i];
}

extern "C" void kernel_launch(void* const* d_in, const int* in_sizes, int n_in,
                              void* d_out, int out_size, void* d_ws, size_t ws_size,
                              hipStream_t stream)
{
    const float* x     = (const float*)d_in[0];
    const float* eWih  = (const float*)d_in[1];
    const float* eWhh  = (const float*)d_in[2];
    const float* ebih  = (const float*)d_in[3];
    const float* ebhh  = (const float*)d_in[4];
    const float* dWih  = (const float*)d_in[5];
    const float* dWhh  = (const float*)d_in[6];
    const float* dbih  = (const float*)d_in[7];
    const float* dbhh  = (const float*)d_in[8];
    const float* h2oW  = (const float*)d_in[9];
    const float* h2ob  = (const float*)d_in[10];
    const float* UW    = (const float*)d_in[11];
    const float* Ub    = (const float*)d_in[12];
    const float* WW    = (const float*)d_in[13];
    const float* Wb    = (const float*)d_in[14];
    const float* attnW = (const float*)d_in[15];
    const float* attnb = (const float*)d_in[16];
    const float* o2hW  = (const float*)d_in[17];
    const float* o2hb  = (const float*)d_in[18];

    float* ws      = (float*)d_ws;
    unsigned* ctrl = (unsigned*)ws;                    // 512 slots (2KB); [256]=flag
    float* zrow    = ws + 512;                         // 2048 zeros (h_0)
    float* enc_out = zrow + H;                         // 512*2048
    float* gi_all  = enc_out + (size_t)T_ * H;         // 512*6144
    float* U       = gi_all + (size_t)T_ * 3 * H;      // 512*2048
    float* Wd      = U + (size_t)T_ * H;               // 2048
    float* scores  = Wd + H;                           // 512
    float* aw      = scores + T_;                      // 512
    float* din     = aw + T_;                          // 4096
    float* hd      = din + 2 * H;                      // 2*2048

    float* outs  = (float*)d_out;                      // 64*128
    float* attns = outs + STEPS * OUT_;                // 64*512

    // zero barrier slots + h0 row (d_ws is poisoned 0xAA before every call)
    hipMemsetAsync(d_ws, 0, (512 + H) * sizeof(float), stream);

    // ---- encoder ----
    gemm_abt<<<dim3(3 * H / BN, T_ / BM), 256, 0, stream>>>(
        x, eWih, ebih, gi_all, T_, 3 * H, IN_);
    enc_persistent<<<256, 512, 0, stream>>>(eWhh, ebhh, gi_all, enc_out, ctrl);

    gemm_abt<<<dim3(H / BN, T_ / BM), 256, 0, stream>>>(
        enc_out, UW, Ub, U, T_, H, H);

    // ---- decoder ----
    copy_kernel<<<8, 256, 0, stream>>>(din, o2hb, H);
    const float* h = enc_out + (size_t)(T_ - 1) * H;
    for (int s = 0; s < STEPS; s++) {
        matvec_kernel<<<64, 512, 0, stream>>>(WW, h, Wb, Wd, H, H);
        scores_kernel<<<T_, 256, 0, stream>>>(U, Wd, attnW, attnb, scores);
        softmax_kernel<<<1, 512, 0, stream>>>(scores, aw, attns + (size_t)s * T_,
                                              din + H);
        ctx_kernel<<<dim3(8, 4), 256, 0, stream>>>(aw, enc_out, din + H);
        float* hn = hd + (s & 1) * H;
        dec_gru_kernel<<<256, 512, 0, stream>>>(dWih, dWhh, dbih, dbhh, din, h, hn);
        logits_kernel<<<1, 256, 0, stream>>>(h2oW, h2ob, hn, o2hW, o2hb,
                                             outs + (size_t)s * OUT_, din);
        h = hn;
    }
}

// Round 6
// 8541.315 us; speedup vs baseline: 2.2026x; 1.8963x over previous
//
#include <hip/hip_runtime.h>
#include <math.h>

// Sizes fixed by setup_inputs(): H=2048, IN=128, OUT=128, T=512, STEPS=64
#define H    2048
#define IN_  128
#define OUT_ 128
#define T_   512
#define STEPS 64

// ---------------------------------------------------------------------------
// Generic tiled GEMM: C[M,N] = A[M,K] @ B[N,K]^T + bias[N]   (all row-major)
// ---------------------------------------------------------------------------
#define BM 64
#define BN 64
#define BK 16
__global__ __launch_bounds__(256) void gemm_abt(
    const float* __restrict__ A, const float* __restrict__ B,
    const float* __restrict__ bias, float* __restrict__ C,
    int M, int N, int K)
{
    __shared__ float As[BM][BK + 1];
    __shared__ float Bs[BN][BK + 1];
    int tid = threadIdx.x;
    int m0 = blockIdx.y * BM, n0 = blockIdx.x * BN;
    int ty = tid / 16, tx = tid % 16;
    float acc[4][4] = {};
    int r = tid >> 2, q = tid & 3;
    for (int k0 = 0; k0 < K; k0 += BK) {
        float4 a4 = *(const float4*)(A + (size_t)(m0 + r) * K + k0 + q * 4);
        As[r][q * 4 + 0] = a4.x; As[r][q * 4 + 1] = a4.y;
        As[r][q * 4 + 2] = a4.z; As[r][q * 4 + 3] = a4.w;
        float4 b4 = *(const float4*)(B + (size_t)(n0 + r) * K + k0 + q * 4);
        Bs[r][q * 4 + 0] = b4.x; Bs[r][q * 4 + 1] = b4.y;
        Bs[r][q * 4 + 2] = b4.z; Bs[r][q * 4 + 3] = b4.w;
        __syncthreads();
#pragma unroll
        for (int kk = 0; kk < BK; kk++) {
            float a[4], b[4];
#pragma unroll
            for (int i = 0; i < 4; i++) a[i] = As[ty * 4 + i][kk];
#pragma unroll
            for (int j = 0; j < 4; j++) b[j] = Bs[tx * 4 + j][kk];
#pragma unroll
            for (int i = 0; i < 4; i++)
#pragma unroll
                for (int j = 0; j < 4; j++) acc[i][j] += a[i] * b[j];
        }
        __syncthreads();
    }
#pragma unroll
    for (int i = 0; i < 4; i++)
#pragma unroll
        for (int j = 0; j < 4; j++)
            C[(size_t)(m0 + ty * 4 + i) * N + n0 + tx * 4 + j] =
                acc[i][j] + bias[n0 + tx * 4 + j];
}

// ---------------------------------------------------------------------------
// Persistent encoder: 256 blocks x 512 threads, 1 block/CU.
// Block b owns hidden units j0=8b..j0+7 (24 rows of Whh register-resident).
//
// FENCE-FREE cross-block dataflow (R5 lesson): R2-R5 all cost ~25us/step
// regardless of barrier protocol; the invariant was 2 agent-scope fences
// per step, which lower to buffer_wbl2/buffer_inv (full per-XCD L2
// writeback/invalidate). Evidence relaxed agent atomics alone propagate
// cross-XCD: the barrier FLAGS already did, fenceless, in R3-R5.
// So: h itself moves via relaxed agent-scope atomic dword ops (sc1,
// coherent at Infinity Cache, bypassing stale L1/L2). Producer ordering
// (h stores -> slot store) is wave-0-local via fence(release,"workgroup")
// = s_waitcnt only, no cache ops. NO agent fences anywhere in the loop.
// ---------------------------------------------------------------------------
__global__ __launch_bounds__(512, 1) void enc_persistent(
    const float* __restrict__ Whh, const float* __restrict__ bhh,
    const float* __restrict__ gi_all, float* __restrict__ enc_out,
    unsigned* __restrict__ ctrl)
{
    __shared__ float h_s[H];
    __shared__ float red_s[24];
    const int tid = threadIdx.x;
    const int wv = tid >> 6, ln = tid & 63;
    const int j0 = blockIdx.x * 8;
    unsigned* enc_u = (unsigned*)enc_out;

    // ---- one-time: weights -> registers (coalesced float4 loads) ----
    float4 wreg[3][8];
    float bias[3];
    int sidx[3];
#pragma unroll
    for (int i = 0; i < 3; i++) {
        int ridx = wv * 3 + i;            // 0..23
        int u = ridx & 7, g = ridx >> 3;  // gate 0=r,1=z,2=n
        int row = g * H + j0 + u;
        const float4* wr = (const float4*)(Whh + (size_t)row * H);
#pragma unroll
        for (int m = 0; m < 8; m++) wreg[i][m] = wr[ln + (m << 6)];
        bias[i] = bhh[row];
        sidx[i] = g * 8 + u;
    }

    for (int t = 0; t < T_; t++) {
        // h_{t-1} -> LDS via relaxed agent atomic dword loads (IC-coherent).
        // 4 loads/thread, unit-stride across lanes per load.
        {
            const size_t base = (size_t)(t - 1) * H;  // t=0 reads zero row
#pragma unroll
            for (int k = 0; k < 4; k++) {
                unsigned u = __hip_atomic_load(
                    &enc_u[base + tid + 512 * k], __ATOMIC_RELAXED,
                    __HIP_MEMORY_SCOPE_AGENT);
                h_s[tid + 512 * k] = __uint_as_float(u);
            }
        }
        float ir = 0.f, iz = 0.f, inn = 0.f;
        if (tid < 8) {
            const float* gi = gi_all + (size_t)t * 3 * H;
            ir  = gi[j0 + tid];
            iz  = gi[H + j0 + tid];
            inn = gi[2 * H + j0 + tid];
        }
        __syncthreads();

        float s0 = 0.f, s1 = 0.f, s2 = 0.f;
#pragma unroll
        for (int m = 0; m < 8; m++) {
            float4 h4 = ((const float4*)h_s)[ln + (m << 6)];
            s0 += wreg[0][m].x * h4.x + wreg[0][m].y * h4.y +
                  wreg[0][m].z * h4.z + wreg[0][m].w * h4.w;
            s1 += wreg[1][m].x * h4.x + wreg[1][m].y * h4.y +
                  wreg[1][m].z * h4.z + wreg[1][m].w * h4.w;
            s2 += wreg[2][m].x * h4.x + wreg[2][m].y * h4.y +
                  wreg[2][m].z * h4.z + wreg[2][m].w * h4.w;
        }
#pragma unroll
        for (int off = 32; off; off >>= 1) {
            s0 += __shfl_xor(s0, off, 64);
            s1 += __shfl_xor(s1, off, 64);
            s2 += __shfl_xor(s2, off, 64);
        }
        if (ln == 0) {
            red_s[sidx[0]] = s0 + bias[0];
            red_s[sidx[1]] = s1 + bias[1];
            red_s[sidx[2]] = s2 + bias[2];
        }
        __syncthreads();

        // h write (wave 0, lanes 0..7) via relaxed agent atomic stores,
        // then SAME WAVE: waitcnt (workgroup release) + arrival-slot store.
        if (tid < 8) {
            float hr = red_s[tid], hz = red_s[8 + tid], hn = red_s[16 + tid];
            float rg = 1.f / (1.f + expf(-(ir + hr)));
            float zg = 1.f / (1.f + expf(-(iz + hz)));
            float ng = tanhf(inn + rg * hn);
            float hv = (1.f - zg) * ng + zg * h_s[j0 + tid];
            __hip_atomic_store(&enc_u[(size_t)t * H + j0 + tid],
                               __float_as_uint(hv), __ATOMIC_RELAXED,
                               __HIP_MEMORY_SCOPE_AGENT);
        }
        if (tid == 0) {
            // s_waitcnt vmcnt(0) only — orders wave-0's h stores before the
            // slot store at the IC coherence point. No L2 writeback.
            __builtin_amdgcn_fence(__ATOMIC_RELEASE, "workgroup");
            __hip_atomic_store(&ctrl[blockIdx.x], (unsigned)(t + 1),
                               __ATOMIC_RELAXED, __HIP_MEMORY_SCOPE_AGENT);
        }

        // ---- two-level flag barrier, all relaxed agent atomics ----
        if (blockIdx.x == 0) {
            if (tid < 256) {
                while (__hip_atomic_load(&ctrl[tid], __ATOMIC_RELAXED,
                                         __HIP_MEMORY_SCOPE_AGENT) <
                       (unsigned)(t + 1))
                    __builtin_amdgcn_s_sleep(1);
            }
            __syncthreads();
            if (tid == 0)
                __hip_atomic_store(&ctrl[256], (unsigned)(t + 1),
                                   __ATOMIC_RELAXED, __HIP_MEMORY_SCOPE_AGENT);
        } else {
            if (tid == 0) {
                while (__hip_atomic_load(&ctrl[256], __ATOMIC_RELAXED,
                                         __HIP_MEMORY_SCOPE_AGENT) <
                       (unsigned)(t + 1))
                    __builtin_amdgcn_s_sleep(4);
            }
        }
        __builtin_amdgcn_fence(__ATOMIC_ACQUIRE, "workgroup");  // compiler order only
        __syncthreads();
    }
}

// ---------------------------------------------------------------------------
// Decoder GRU step (unchanged).
// ---------------------------------------------------------------------------
__global__ __launch_bounds__(512) void dec_gru_kernel(
    const float* __restrict__ Wih, const float* __restrict__ Whh,
    const float* __restrict__ bih, const float* __restrict__ bhh,
    const float* __restrict__ din, const float* __restrict__ h_prev,
    float* __restrict__ h_out)
{
    __shared__ float d_s[2 * H];
    __shared__ float h_s[H];
    __shared__ float red_s[48];
    int tid = threadIdx.x;
    ((float4*)d_s)[tid]       = ((const float4*)din)[tid];
    ((float4*)d_s)[tid + 512] = ((const float4*)din)[tid + 512];
    ((float4*)h_s)[tid]       = ((const float4*)h_prev)[tid];
    __syncthreads();
    int wave = tid >> 6, lane = tid & 63;
    int j0 = blockIdx.x * 8;
#pragma unroll
    for (int i = 0; i < 6; i++) {
        int ridx = i * 8 + wave;
        int big = (ridx < 24);
        int rr = big ? ridx : ridx - 24;
        int u = rr & 7, g = rr >> 3;
        int row = g * H + j0 + u;
        float sum = 0.f, bs;
        if (big) {
            const float4* wr = (const float4*)(Wih + (size_t)row * (2 * H));
            const float4* dv = (const float4*)d_s;
#pragma unroll
            for (int k = 0; k < 16; k++) {
                float4 w4 = wr[lane + 64 * k];
                float4 v4 = dv[lane + 64 * k];
                sum += w4.x * v4.x + w4.y * v4.y + w4.z * v4.z + w4.w * v4.w;
            }
            bs = bih[row];
        } else {
            const float4* wr = (const float4*)(Whh + (size_t)row * H);
            const float4* hv = (const float4*)h_s;
#pragma unroll
            for (int k = 0; k < 8; k++) {
                float4 w4 = wr[lane + 64 * k];
                float4 h4 = hv[lane + 64 * k];
                sum += w4.x * h4.x + w4.y * h4.y + w4.z * h4.z + w4.w * h4.w;
            }
            bs = bhh[row];
        }
#pragma unroll
        for (int off = 32; off; off >>= 1) sum += __shfl_xor(sum, off, 64);
        if (lane == 0) red_s[ridx] = sum + bs;
    }
    __syncthreads();
    if (tid < 8) {
        int j = j0 + tid;
        float ir = red_s[tid], iz = red_s[8 + tid], inn = red_s[16 + tid];
        float hr = red_s[24 + tid], hz = red_s[32 + tid], hn = red_s[40 + tid];
        float rg = 1.f / (1.f + expf(-(ir + hr)));
        float zg = 1.f / (1.f + expf(-(iz + hz)));
        float ng = tanhf(inn + rg * hn);
        h_out[j] = (1.f - zg) * ng + zg * h_s[j];
    }
}

__global__ __launch_bounds__(512) void matvec_kernel(
    const float* __restrict__ W, const float* __restrict__ v,
    const float* __restrict__ bias, float* __restrict__ out,
    int nrows, int K)
{
    __shared__ float v_s[4096];
    int tid = threadIdx.x;
    for (int i = tid; i < (K >> 2); i += blockDim.x)
        ((float4*)v_s)[i] = ((const float4*)v)[i];
    __syncthreads();
    int lane = tid & 63;
    int gw = (blockIdx.x * blockDim.x + tid) >> 6;
    int nw = (gridDim.x * blockDim.x) >> 6;
    int kq = K >> 2;
    for (int row = gw; row < nrows; row += nw) {
        const float4* wr = (const float4*)(W + (size_t)row * K);
        const float4* vv = (const float4*)v_s;
        float sum = 0.f;
        for (int k = lane; k < kq; k += 64) {
            float4 w4 = wr[k]; float4 h4 = vv[k];
            sum += w4.x * h4.x + w4.y * h4.y + w4.z * h4.z + w4.w * h4.w;
        }
#pragma unroll
        for (int off = 32; off; off >>= 1) sum += __shfl_xor(sum, off, 64);
        if (lane == 0) out[row] = sum + bias[row];
    }
}

__global__ __launch_bounds__(256) void scores_kernel(
    const float* __restrict__ U, const float* __restrict__ Wd,
    const float* __restrict__ attn_W, const float* __restrict__ attn_b,
    float* __restrict__ scores)
{
    int t = blockIdx.x, tid = threadIdx.x;
    int wave = tid >> 6, lane = tid & 63;
    const float* Ut = U + (size_t)t * H;
    float p = 0.f;
    for (int j = tid; j < H; j += 256)
        p += tanhf(Ut[j] + Wd[j]) * attn_W[j];
#pragma unroll
    for (int off = 32; off; off >>= 1) p += __shfl_xor(p, off, 64);
    __shared__ float ws_[4];
    if (lane == 0) ws_[wave] = p;
    __syncthreads();
    if (tid == 0) scores[t] = ws_[0] + ws_[1] + ws_[2] + ws_[3] + attn_b[0];
}

__global__ __launch_bounds__(512) void softmax_kernel(
    const float* __restrict__ scores, float* __restrict__ aw,
    float* __restrict__ attn_out, float* __restrict__ din_ctx)
{
    __shared__ float red[8];
    __shared__ float m_sh, s_sh;
    int tid = threadIdx.x, wave = tid >> 6, lane = tid & 63;
    float s = scores[tid];
    float m = s;
#pragma unroll
    for (int off = 32; off; off >>= 1) m = fmaxf(m, __shfl_xor(m, off, 64));
    if (lane == 0) red[wave] = m;
    __syncthreads();
    if (tid == 0) {
        float mm = red[0];
        for (int i = 1; i < 8; i++) mm = fmaxf(mm, red[i]);
        m_sh = mm;
    }
    __syncthreads();
    float e = expf(s - m_sh);
    float p = e;
#pragma unroll
    for (int off = 32; off; off >>= 1) p += __shfl_xor(p, off, 64);
    if (lane == 0) red[wave] = p;
    __syncthreads();
    if (tid == 0) {
        float ss = 0.f;
        for (int i = 0; i < 8; i++) ss += red[i];
        s_sh = ss;
    }
    __syncthreads();
    float a = e / s_sh;
    aw[tid] = a;
    attn_out[tid] = a;
    din_ctx[tid] = 0.f; din_ctx[tid + 512] = 0.f;
    din_ctx[tid + 1024] = 0.f; din_ctx[tid + 1536] = 0.f;
}

__global__ __launch_bounds__(256) void ctx_kernel(
    const float* __restrict__ aw, const float* __restrict__ enc_out,
    float* __restrict__ din_ctx)
{
    int j = blockIdx.x * 256 + threadIdx.x;
    int t0 = blockIdx.y * 128;
    __shared__ float aw_s[128];
    if (threadIdx.x < 128) aw_s[threadIdx.x] = aw[t0 + threadIdx.x];
    __syncthreads();
    float acc = 0.f;
#pragma unroll 8
    for (int t = 0; t < 128; t++)
        acc += aw_s[t] * enc_out[(size_t)(t0 + t) * H + j];
    atomicAdd(&din_ctx[j], acc);
}

__global__ __launch_bounds__(256) void logits_kernel(
    const float* __restrict__ h2o_W, const float* __restrict__ h2o_b,
    const float* __restrict__ h2,
    const float* __restrict__ o2h_W, const float* __restrict__ o2h_b,
    float* __restrict__ out_row, float* __restrict__ din_emb)
{
    __shared__ float h_s[H];
    __shared__ float lg[OUT_];
    __shared__ float m_s, ls_s;
    __shared__ int am_s;
    int tid = threadIdx.x;
    ((float4*)h_s)[tid]       = ((const float4*)h2)[tid];
    ((float4*)h_s)[tid + 256] = ((const float4*)h2)[tid + 256];
    __syncthreads();
    int wave = tid >> 6, lane = tid & 63;
#pragma unroll
    for (int i = 0; i < 32; i++) {
        int row = i * 4 + wave;
        const float4* wr = (const float4*)(h2o_W + (size_t)row * H);
        const float4* hv = (const float4*)h_s;
        float sum = 0.f;
#pragma unroll
        for (int k = 0; k < 8; k++) {
            float4 w4 = wr[lane + 64 * k];
            float4 h4 = hv[lane + 64 * k];
            sum += w4.x * h4.x + w4.y * h4.y + w4.z * h4.z + w4.w * h4.w;
        }
#pragma unroll
        for (int off = 32; off; off >>= 1) sum += __shfl_xor(sum, off, 64);
        if (lane == 0) lg[row] = sum + h2o_b[row];
    }
    __syncthreads();
    if (tid == 0) {
        float m = lg[0]; int am = 0;
        for (int i = 1; i < OUT_; i++)
            if (lg[i] > m) { m = lg[i]; am = i; }
        float ss = 0.f;
        for (int i = 0; i < OUT_; i++) ss += expf(lg[i] - m);
        m_s = m; ls_s = logf(ss); am_s = am;
    }
    __syncthreads();
    if (tid < OUT_) out_row[tid] = (lg[tid] - m_s) - ls_s;
    int am = am_s;
    for (int j = tid; j < H; j += 256)
        din_emb[j] = o2h_W[(size_t)j * OUT_ + am] + o2h_b[j];
}

__global__ void copy_kernel(float* dst, const float* src, int n) {
    int i = blockIdx.x * blockDim.x + threadIdx.x;
    if (i < n) dst[i] = src[i];
}

extern "C" void kernel_launch(void* const* d_in, const int* in_sizes, int n_in,
                              void* d_out, int out_size, void* d_ws, size_t ws_size,
                              hipStream_t stream)
{
    const float* x     = (const float*)d_in[0];
    const float* eWih  = (const float*)d_in[1];
    const float* eWhh  = (const float*)d_in[2];
    const float* ebih  = (const float*)d_in[3];
    const float* ebhh  = (const float*)d_in[4];
    const float* dWih  = (const float*)d_in[5];
    const float* dWhh  = (const float*)d_in[6];
    const float* dbih  = (const float*)d_in[7];
    const float* dbhh  = (const float*)d_in[8];
    const float* h2oW  = (const float*)d_in[9];
    const float* h2ob  = (const float*)d_in[10];
    const float* UW    = (const float*)d_in[11];
    const float* Ub    = (const float*)d_in[12];
    const float* WW    = (const float*)d_in[13];
    const float* Wb    = (const float*)d_in[14];
    const float* attnW = (const float*)d_in[15];
    const float* attnb = (const float*)d_in[16];
    const float* o2hW  = (const float*)d_in[17];
    const float* o2hb  = (const float*)d_in[18];

    float* ws      = (float*)d_ws;
    unsigned* ctrl = (unsigned*)ws;                    // 512 slots (2KB); [256]=flag
    float* zrow    = ws + 512;                         // 2048 zeros (h_0)
    float* enc_out = zrow + H;                         // 512*2048
    float* gi_all  = enc_out + (size_t)T_ * H;         // 512*6144
    float* U       = gi_all + (size_t)T_ * 3 * H;      // 512*2048
    float* Wd      = U + (size_t)T_ * H;               // 2048
    float* scores  = Wd + H;                           // 512
    float* aw      = scores + T_;                      // 512
    float* din     = aw + T_;                          // 4096
    float* hd      = din + 2 * H;                      // 2*2048

    float* outs  = (float*)d_out;                      // 64*128
    float* attns = outs + STEPS * OUT_;                // 64*512

    // zero barrier slots + h0 row (d_ws is poisoned 0xAA before every call)
    hipMemsetAsync(d_ws, 0, (512 + H) * sizeof(float), stream);

    // ---- encoder ----
    gemm_abt<<<dim3(3 * H / BN, T_ / BM), 256, 0, stream>>>(
        x, eWih, ebih, gi_all, T_, 3 * H, IN_);
    enc_persistent<<<256, 512, 0, stream>>>(eWhh, ebhh, gi_all, enc_out, ctrl);

    gemm_abt<<<dim3(H / BN, T_ / BM), 256, 0, stream>>>(
        enc_out, UW, Ub, U, T_, H, H);

    // ---- decoder ----
    copy_kernel<<<8, 256, 0, stream>>>(din, o2hb, H);
    const float* h = enc_out + (size_t)(T_ - 1) * H;
    for (int s = 0; s < STEPS; s++) {
        matvec_kernel<<<64, 512, 0, stream>>>(WW, h, Wb, Wd, H, H);
        scores_kernel<<<T_, 256, 0, stream>>>(U, Wd, attnW, attnb, scores);
        softmax_kernel<<<1, 512, 0, stream>>>(scores, aw, attns + (size_t)s * T_,
                                              din + H);
        ctx_kernel<<<dim3(8, 4), 256, 0, stream>>>(aw, enc_out, din + H);
        float* hn = hd + (s & 1) * H;
        dec_gru_kernel<<<256, 512, 0, stream>>>(dWih, dWhh, dbih, dbhh, din, h, hn);
        logits_kernel<<<1, 256, 0, stream>>>(h2oW, h2ob, hn, o2hW, o2hb,
                                             outs + (size_t)s * OUT_, din);
        h = hn;
    }
}